// Round 6
// baseline (18878.545 us; speedup 1.0000x reference)
//
#include <hip/hip_runtime.h>

// LSTM-VAE  B=64 T=256 D=1024 L=2 G=128 — persistent kernel.
// h-exchange: write-through coherent stores (sc0 sc1) + NORMAL cached loads
// + per-step acquire fence (buffer_inv) inside the grid barrier, so the
// per-XCD L2 serves the 128-way A-broadcast instead of the fabric/LLC.
#define B_  64
#define T_  256
#define D_  1024
#define G_  128
#define FD  4096   // 4*D
#define K2  2048   // D (ih) + D (hh)
#define BD  65536  // B_*D_
#define NWG 256

typedef unsigned short u16;
typedef __attribute__((ext_vector_type(8))) short frag8;  // 8 bf16
typedef __attribute__((ext_vector_type(4))) float f4;

__device__ __forceinline__ u16 f2b(float f) {
  unsigned u = __float_as_uint(f);
  u += 0x7fffu + ((u >> 16) & 1u);
  return (u16)(u >> 16);
}
__device__ __forceinline__ float b2f(u16 s) {
  return __uint_as_float(((unsigned)s) << 16);
}
__device__ __forceinline__ float sigm(float x) { return 1.0f / (1.0f + __expf(-x)); }

// write-through coherent store (visible at LLC once vmcnt drains)
__device__ __forceinline__ void stcoh(unsigned* p, unsigned w) {
  asm volatile("global_store_dword %0, %1, off sc0 sc1"
               :: "v"(p), "v"(w) : "memory");
}

// ---------------- 2-level grid barrier + acquire-invalidate -----------------
// cnt: 64 counters, 128B apart (4 WGs each). rel: release word. ep: 1-based.
// On exit every thread has executed an agent-acquire fence: L1/L2 stale lines
// dropped, so subsequent NORMAL loads observe the write-through h data.
__device__ __forceinline__ void lightbar(unsigned* cnt, unsigned* rel,
                                         unsigned ep, int wg) {
  asm volatile("s_waitcnt vmcnt(0)" ::: "memory");   // drain sc0sc1 stores
  __syncthreads();
  const int tid = threadIdx.x;
  if (tid == 0)
    __hip_atomic_fetch_add(&cnt[(wg & 63) * 32], 1u, __ATOMIC_RELAXED,
                           __HIP_MEMORY_SCOPE_AGENT);
  if (wg == 0) {
    if (tid < 64) {
      while (__hip_atomic_load(&cnt[tid * 32], __ATOMIC_RELAXED,
                               __HIP_MEMORY_SCOPE_AGENT) < ep * 4u)
        __builtin_amdgcn_s_sleep(1);
    }
    __syncthreads();
    if (tid == 0)
      __hip_atomic_store(rel, ep, __ATOMIC_RELAXED, __HIP_MEMORY_SCOPE_AGENT);
  } else {
    if (tid == 0) {
      while (__hip_atomic_load(rel, __ATOMIC_RELAXED,
                               __HIP_MEMORY_SCOPE_AGENT) < ep)
        __builtin_amdgcn_s_sleep(1);
    }
  }
  __syncthreads();
  __builtin_amdgcn_fence(__ATOMIC_ACQUIRE, "agent");   // buffer_inv: fresh view
}

// heavyweight barrier for phase transitions (normal dirty stores cross here)
__device__ __forceinline__ void fencedbar(unsigned* cnt, unsigned* rel,
                                          unsigned ep, int wg) {
  __builtin_amdgcn_fence(__ATOMIC_RELEASE, "agent");   // wbl2
  lightbar(cnt, rel, ep, wg);
}

// ---------------- weight slice load: 32 rows x 2048 bf16, XOR-swizzled ------
__device__ __forceinline__ void load_weights(const u16* __restrict__ Wg, char* wlds) {
  const int t  = threadIdx.x;
  const int r  = t >> 4;           // 0..31
  const int c0 = t & 15;
  const char* src = (const char*)(Wg + (long)r * K2);
  char* dstrow = wlds + (r << 12);
  const int swz = (r & 7) << 4;
  #pragma unroll
  for (int i = 0; i < 16; ++i) {
    const int cb = (c0 + (i << 4)) << 4;      // chunk byte offset
    frag8 v = *(const frag8*)(src + cb);
    *(frag8*)(dstrow + (cb ^ swz)) = v;
  }
  __syncthreads();
}

// ---------------- one LSTM cell for this WG's 8 units -----------------------
// A0 (k<1024), A1 (k>=1024); both read with NORMAL cached loads.
__device__ __forceinline__ void cell(
    const u16* __restrict__ A0, const u16* __restrict__ A1,
    const char* wlds, float* gl,
    float& c_reg, const f4& bias, int ug0,
    u16* __restrict__ hout, float* __restrict__ fout, long fstride)
{
  const int tid = threadIdx.x;
  const int lane = tid & 63, wv = tid >> 6;
  const int mt = wv & 3, kh = wv >> 2;
  const int l15 = lane & 15, lgr = lane >> 4;

  f4 acc0 = (f4){0.f,0.f,0.f,0.f}, acc1 = (f4){0.f,0.f,0.f,0.f};
  const u16* Ab = kh ? A1 : A0;
  if (Ab) {
    const u16* ap = Ab + (mt * 16 + l15) * 1024 + lgr * 8;
    const int kbyte0 = (kh << 11) + (lgr << 4);
    const int swz = (l15 & 7) << 4;
    const char* w0r = wlds + ((long)l15 << 12);
    const char* w1r = wlds + ((long)(16 + l15) << 12);
    #pragma unroll 8
    for (int kk = 0; kk < 32; ++kk) {
      frag8 af = *(const frag8*)(ap + kk * 32);
      const int kb = (kbyte0 + (kk << 6)) ^ swz;
      frag8 b0 = *(const frag8*)(w0r + kb);
      frag8 b1 = *(const frag8*)(w1r + kb);
      acc0 = __builtin_amdgcn_mfma_f32_16x16x32_bf16(af, b0, acc0, 0, 0, 0);
      acc1 = __builtin_amdgcn_mfma_f32_16x16x32_bf16(af, b1, acc1, 0, 0, 0);
    }
  }
  float* g = gl + kh * (64 * 32);
  const int orow = mt * 16 + lgr * 4;
  #pragma unroll
  for (int r = 0; r < 4; ++r) {
    g[(orow + r) * 32 + l15]      = acc0[r];
    g[(orow + r) * 32 + 16 + l15] = acc1[r];
  }
  __syncthreads();

  const int row = tid >> 3, ul = tid & 7;
  f4 p0 = *(const f4*)(gl + row * 32 + ul * 4);
  f4 p1 = *(const f4*)(gl + 64 * 32 + row * 32 + ul * 4);
  float iv = p0.x + p1.x + bias.x;
  float fv = p0.y + p1.y + bias.y;
  float gv = p0.z + p1.z + bias.z;
  float ov = p0.w + p1.w + bias.w;
  float cn = sigm(fv) * c_reg + sigm(iv) * tanhf(gv);
  float hh = sigm(ov) * tanhf(cn);
  c_reg = cn;
  // coherent paired u16 store (even lane stores the u32 word)
  unsigned hv = (unsigned)f2b(hh);
  unsigned other = __shfl_xor(hv, 1);
  if (!(ul & 1)) {
    unsigned word = hv | (other << 16);
    stcoh((unsigned*)(hout + row * 1024 + ug0 + ul), word);
  }
  if (fout) fout[(long)row * fstride + ug0 + ul] = hh;
  __syncthreads();   // protect gl for next cell
}

// ---------------- VAE head, one (s,l,b) per WG ------------------------------
__device__ __forceinline__ void vae_wg(
    int bid, char* scr,
    const u16* h0f, const u16* h1f, const float* c0f, const float* c1f,
    const float* hmuW, const float* hmub, const float* hsgW, const float* hsgb,
    const float* houtW, const float* houtb,
    const float* cmuW, const float* cmub, const float* csgW, const float* csgb,
    const float* coutW, const float* coutb,
    const float* eps_h, const float* eps_c,
    float* muo, float* sgo, u16* hd0, u16* hd1, float* cd0, float* cd1)
{
  float* hrow = (float*)scr;
  float* muv  = hrow + 1024;
  float* sgv  = muv + 128;
  float* zz   = sgv + 128;
  const int tid = threadIdx.x;
  const int b = bid & 63, l = (bid >> 6) & 1, s = bid >> 7;

  if (s == 0) {
    const u16* h = (l ? h1f : h0f) + b * D_;
    for (int i = tid; i < D_; i += 512) hrow[i] = b2f(h[i]);
  } else {
    const float* c = (l ? c1f : c0f) + b * D_;
    for (int i = tid; i < D_; i += 512) hrow[i] = c[i];
  }
  __syncthreads();

  const float* muW = (s ? cmuW : hmuW) + (long)l * G_ * D_;
  const float* sgW = (s ? csgW : hsgW) + (long)l * G_ * D_;
  const float* mub = (s ? cmub : hmub) + l * G_;
  const float* sgb = (s ? csgb : hsgb) + l * G_;
  const int wv = tid >> 6, lane = tid & 63;
  for (int oi = wv; oi < 2 * G_; oi += 8) {
    const int g = (oi < G_) ? oi : oi - G_;
    const float* Wr = ((oi < G_) ? muW : sgW) + (long)g * D_;
    float d = 0.f;
    for (int j = lane; j < D_; j += 64) d += Wr[j] * hrow[j];
    for (int off = 1; off < 64; off <<= 1) d += __shfl_xor(d, off);
    if (lane == 0) {
      if (oi < G_) muv[g] = d + mub[g]; else sgv[g] = d + sgb[g];
    }
  }
  __syncthreads();
  if (tid < G_) {
    const int g = tid;
    const float mu = muv[g], sg = sgv[g];
    const float* ep = (s ? eps_c : eps_h) + ((long)l * B_ + b) * G_;
    zz[g] = mu + ep[g] * __expf(sg);
    muo[(long)bid * G_ + g] = mu;
    sgo[(long)bid * G_ + g] = sg;
  }
  __syncthreads();
  const float* oW  = (s ? coutW : houtW) + (long)l * D_ * G_;
  const float* obv = (s ? coutb : houtb) + l * D_;
  for (int i = 0; i < 2; ++i) {
    const int dd = i * 512 + tid;
    float acc = obv[dd];
    const float* Wr = oW + (long)dd * G_;
    #pragma unroll 4
    for (int g = 0; g < G_; ++g) acc += zz[g] * Wr[g];
    if (s == 0) { (l ? hd1 : hd0)[b * D_ + dd] = f2b(acc); }
    else        { (l ? cd1 : cd0)[b * D_ + dd] = acc; }
  }
  __syncthreads();
}

// ---------------- the persistent kernel -------------------------------------
__global__ __launch_bounds__(512, 1)
void persist(const u16* __restrict__ Wpe, const u16* __restrict__ Wpd,
             const float* __restrict__ bp,
             const u16* __restrict__ xb, const u16* __restrict__ xd0,
             u16* H0e, u16* h1e, u16* h0d, u16* yb,
             float* ce0, float* ce1,
             u16* hd0i, u16* hd1i, float* cd0, float* cd1,
             const float* hmuW, const float* hmub, const float* hsgW, const float* hsgb,
             const float* houtW, const float* houtb,
             const float* cmuW, const float* cmub, const float* csgW, const float* csgb,
             const float* coutW, const float* coutb,
             const float* eps_h, const float* eps_c,
             float* out, float* muo, float* sgo, unsigned* bar)
{
  __shared__ __align__(16) char smem[147456];   // 128K weights + 16K scratch
  char*  wlds = smem;
  float* gl   = (float*)(smem + 131072);

  unsigned* cnt = bar;          // 64 counters * 32 u32 stride
  unsigned* rel = bar + 2048;

  const int wg  = blockIdx.x;
  const bool isL0 = (wg < 128);
  const int wgL = wg & 127;
  const int ug0 = wgL * 8;
  const int tid = threadIdx.x;
  unsigned ep = 0;

  // ---- encoder phase ----
  load_weights(Wpe + (isL0 ? 0l : (long)FD * K2) + (long)wgL * 32 * K2, wlds);
  f4 bias = *(const f4*)(bp + (isL0 ? 0 : FD) + (ug0 + (tid & 7)) * 4);
  float c_reg = 0.f;

  for (int s = 0; s <= 256; ++s) {
    if (isL0) {
      if (s < 256)
        cell(xb + (long)s * BD,
             s ? (H0e + (long)((s - 1) & 1) * BD) : nullptr,
             wlds, gl, c_reg, bias, ug0,
             H0e + (long)(s & 1) * BD, nullptr, 0);
    } else {
      if (s >= 1)
        cell(H0e + (long)((s - 1) & 1) * BD,
             (s >= 2) ? (h1e + (long)((s - 2) & 1) * BD) : nullptr,
             wlds, gl, c_reg, bias, ug0,
             h1e + (long)((s - 1) & 1) * BD, nullptr, 0);
    }
    lightbar(cnt, rel, ++ep, wg);
  }
  // publish final c (normal stores; fenced barrier follows)
  {
    const int row = tid >> 3, ul = tid & 7;
    (isL0 ? ce0 : ce1)[row * D_ + ug0 + ul] = c_reg;
  }
  fencedbar(cnt, rel, ++ep, wg);

  // ---- VAE ----
  vae_wg(wg, (char*)gl,
         H0e + (long)1 * BD, h1e + (long)1 * BD, ce0, ce1,
         hmuW, hmub, hsgW, hsgb, houtW, houtb,
         cmuW, cmub, csgW, csgb, coutW, coutb,
         eps_h, eps_c, muo, sgo, hd0i, hd1i, cd0, cd1);
  fencedbar(cnt, rel, ++ep, wg);

  // ---- decoder phase ----
  load_weights(Wpd + (isL0 ? 0l : (long)FD * K2) + (long)wgL * 32 * K2, wlds);
  bias = *(const f4*)(bp + 2 * FD + (isL0 ? 0 : FD) + (ug0 + (tid & 7)) * 4);
  {
    const int row = tid >> 3, ul = tid & 7;
    c_reg = (isL0 ? cd0 : cd1)[row * D_ + ug0 + ul];
  }
  lightbar(cnt, rel, ++ep, wg);

  for (int t = 0; t < T_; ++t) {
    if (isL0)
      cell(t ? (yb + (long)((t - 1) & 1) * BD) : xd0,
           t ? (h0d + (long)((t - 1) & 1) * BD) : hd0i,
           wlds, gl, c_reg, bias, ug0,
           h0d + (long)(t & 1) * BD, nullptr, 0);
    lightbar(cnt, rel, ++ep, wg);
    if (!isL0)
      cell(h0d + (long)(t & 1) * BD,
           t ? (yb + (long)((t - 1) & 1) * BD) : hd1i,
           wlds, gl, c_reg, bias, ug0,
           yb + (long)(t & 1) * BD, out + (long)t * D_, (long)T_ * D_);
    lightbar(cnt, rel, ++ep, wg);
  }
}

// ---------------------------------------------------------------------------
// Spectral norm prepass (unchanged, verified)
// ---------------------------------------------------------------------------
__device__ __forceinline__ const float* selW(int m, const float* a, const float* b,
                                             const float* c, const float* d) {
  const float* W;
  switch (m >> 1) { case 0: W = a; break; case 1: W = b; break;
                    case 2: W = c; break; default: W = d; }
  return W + (long)(m & 1) * FD * D_;
}
__device__ __forceinline__ const float* selU(int m, const float* a, const float* b,
                                             const float* c, const float* d) {
  const float* u;
  switch (m >> 1) { case 0: u = a; break; case 1: u = b; break;
                    case 2: u = c; break; default: u = d; }
  return u + (m & 1) * FD;
}

__global__ __launch_bounds__(256)
void k_unorm(const float* euih, const float* euhh, const float* duih, const float* duhh,
             float* uinv)
{
  const int m = blockIdx.x;
  const float* u = selU(m, euih, euhh, duih, duhh);
  float s = 0.f;
  for (int i = threadIdx.x; i < FD; i += 256) { float v = u[i]; s += v * v; }
  __shared__ float red[4];
  for (int off = 1; off < 64; off <<= 1) s += __shfl_xor(s, off);
  if ((threadIdx.x & 63) == 0) red[threadIdx.x >> 6] = s;
  __syncthreads();
  if (threadIdx.x == 0)
    uinv[m] = 1.0f / (sqrtf(red[0] + red[1] + red[2] + red[3]) + 1e-12f);
}

__global__ __launch_bounds__(256)
void k_v(const float* eWih, const float* eWhh, const float* dWih, const float* dWhh,
         const float* euih, const float* euhh, const float* duih, const float* duhh,
         const float* uinv, float* v, float* vss)
{
  __shared__ float us[FD];
  __shared__ float red[4];
  const int m = blockIdx.x >> 2, cb = blockIdx.x & 3;
  const float* W = selW(m, eWih, eWhh, dWih, dWhh);
  const float* u = selU(m, euih, euhh, duih, duhh);
  for (int i = threadIdx.x; i < FD; i += 256) us[i] = u[i];
  __syncthreads();
  const int j = cb * 256 + threadIdx.x;
  float acc = 0.f;
  for (int i = 0; i < FD; ++i) acc += W[(long)i * D_ + j] * us[i];
  acc *= uinv[m];
  v[m * D_ + j] = acc;
  float s = acc * acc;
  for (int off = 1; off < 64; off <<= 1) s += __shfl_xor(s, off);
  if ((threadIdx.x & 63) == 0) red[threadIdx.x >> 6] = s;
  __syncthreads();
  if (threadIdx.x == 0) vss[blockIdx.x] = red[0] + red[1] + red[2] + red[3];
}

__global__ __launch_bounds__(256)
void k_sig(const float* eWih, const float* eWhh, const float* dWih, const float* dWhh,
           const float* v, float* sgp)
{
  __shared__ float vl[D_];
  __shared__ float red[4];
  const int m = blockIdx.x >> 6, rb = blockIdx.x & 63;
  const float* W = selW(m, eWih, eWhh, dWih, dWhh);
  for (int i = threadIdx.x; i < D_; i += 256) vl[i] = v[m * D_ + i];
  __syncthreads();
  const int wv = threadIdx.x >> 6, lane = threadIdx.x & 63;
  float ssq = 0.f;
  for (int rr = 0; rr < 16; ++rr) {
    const int r = rb * 64 + wv * 16 + rr;
    const float* Wr = W + (long)r * D_;
    float d = 0.f;
    for (int j = lane; j < D_; j += 64) d += Wr[j] * vl[j];
    for (int off = 1; off < 64; off <<= 1) d += __shfl_xor(d, off);
    ssq += d * d;
  }
  if (lane == 0) red[wv] = ssq;
  __syncthreads();
  if (threadIdx.x == 0) sgp[blockIdx.x] = red[0] + red[1] + red[2] + red[3];
}

__global__ void k_fin(const float* vss, const float* sgp, float* rsig)
{
  const int m = threadIdx.x;
  if (m < 8) {
    float vn = sqrtf(vss[m * 4] + vss[m * 4 + 1] + vss[m * 4 + 2] + vss[m * 4 + 3]);
    float s2 = 0.f;
    for (int i = 0; i < 64; ++i) s2 += sgp[m * 64 + i];
    rsig[m] = (vn + 1e-12f) / sqrtf(s2);   // 1/sigma
  }
}

__global__ __launch_bounds__(256)
void k_pack(const float* eWih, const float* eWhh, const float* dWih, const float* dWhh,
            const float* rsig, u16* Wpe, u16* Wpd)
{
  const long idx = (long)blockIdx.x * 256 + threadIdx.x;
  const int k8   = (int)(idx & 255);
  const int np   = (int)((idx >> 8) & 4095);
  const int pair = (int)(idx >> 20);
  const int l = pair & 1, ed = pair >> 1;
  const int u = np >> 2, g = np & 3;
  const int srow = g * D_ + u;
  const int k = k8 * 8;
  const float* src; float sc;
  if (k < D_) {
    const float* Wih = ed ? dWih : eWih;
    src = Wih + ((long)(l * FD + srow)) * D_ + k;
    sc  = rsig[ed ? 4 + l : l];
  } else {
    const float* Whh = ed ? dWhh : eWhh;
    src = Whh + ((long)(l * FD + srow)) * D_ + (k - D_);
    sc  = rsig[ed ? 6 + l : 2 + l];
  }
  f4 a = *(const f4*)src;
  f4 b = *(const f4*)(src + 4);
  frag8 o;
  o[0] = (short)f2b(a.x * sc); o[1] = (short)f2b(a.y * sc);
  o[2] = (short)f2b(a.z * sc); o[3] = (short)f2b(a.w * sc);
  o[4] = (short)f2b(b.x * sc); o[5] = (short)f2b(b.y * sc);
  o[6] = (short)f2b(b.z * sc); o[7] = (short)f2b(b.w * sc);
  u16* dst = (ed ? Wpd : Wpe) + ((long)(l * FD + np)) * K2 + k;
  *(frag8*)dst = o;
}

__global__ void k_packb(const float* eb, const float* db, float* bp)
{
  const int idx = blockIdx.x * 256 + threadIdx.x;   // 4*4096
  const int j = idx & 4095, pair = idx >> 12;
  const int l = pair & 1, ed = pair >> 1;
  const float* b = (ed ? db : eb) + l * FD;
  bp[pair * FD + j] = b[(j & 3) * D_ + (j >> 2)];
}

// x [B,T,D] f32 -> xb [T][B][D] bf16
__global__ __launch_bounds__(512)
void k_xb(const float* __restrict__ x, u16* __restrict__ xb)
{
  const long i8 = ((long)blockIdx.x * 512 + threadIdx.x) * 8;
  const int d  = (int)(i8 & 1023);
  const int bt = (int)(i8 >> 10);
  const int b = bt & 63, t = bt >> 6;
  const float* src = x + ((long)b * T_ + t) * D_ + d;
  f4 a = *(const f4*)src;
  f4 c = *(const f4*)(src + 4);
  frag8 o;
  o[0] = (short)f2b(a.x); o[1] = (short)f2b(a.y);
  o[2] = (short)f2b(a.z); o[3] = (short)f2b(a.w);
  o[4] = (short)f2b(c.x); o[5] = (short)f2b(c.y);
  o[6] = (short)f2b(c.z); o[7] = (short)f2b(c.w);
  *(frag8*)(xb + i8) = o;
}

__global__ __launch_bounds__(512)
void k_xd0(const float* __restrict__ initial, u16* __restrict__ xd0)
{
  const int i8 = (blockIdx.x * 512 + threadIdx.x) * 8;   // < 65536
  const int d = i8 & 1023;
  f4 a = *(const f4*)(initial + d);
  f4 c = *(const f4*)(initial + d + 4);
  frag8 o;
  o[0] = (short)f2b(a.x); o[1] = (short)f2b(a.y);
  o[2] = (short)f2b(a.z); o[3] = (short)f2b(a.w);
  o[4] = (short)f2b(c.x); o[5] = (short)f2b(c.y);
  o[6] = (short)f2b(c.z); o[7] = (short)f2b(c.w);
  *(frag8*)(xd0 + i8) = o;
}

// ---------------------------------------------------------------------------
extern "C" void kernel_launch(void* const* d_in, const int* in_sizes, int n_in,
                              void* d_out, int out_size, void* d_ws, size_t ws_size,
                              hipStream_t stream)
{
  const float* x       = (const float*)d_in[0];
  const float* initial = (const float*)d_in[1];
  const float* eWih    = (const float*)d_in[2];
  const float* eWhh    = (const float*)d_in[3];
  const float* eb      = (const float*)d_in[4];
  const float* euih    = (const float*)d_in[5];
  const float* euhh    = (const float*)d_in[6];
  const float* dWih    = (const float*)d_in[7];
  const float* dWhh    = (const float*)d_in[8];
  const float* db      = (const float*)d_in[9];
  const float* duih    = (const float*)d_in[10];
  const float* duhh    = (const float*)d_in[11];
  const float* hmuW    = (const float*)d_in[12];
  const float* hmub    = (const float*)d_in[13];
  const float* hsgW    = (const float*)d_in[14];
  const float* hsgb    = (const float*)d_in[15];
  const float* houtW   = (const float*)d_in[16];
  const float* houtb   = (const float*)d_in[17];
  const float* cmuW    = (const float*)d_in[18];
  const float* cmub    = (const float*)d_in[19];
  const float* csgW    = (const float*)d_in[20];
  const float* csgb    = (const float*)d_in[21];
  const float* coutW   = (const float*)d_in[22];
  const float* coutb   = (const float*)d_in[23];
  const float* eps_h   = (const float*)d_in[24];
  const float* eps_c   = (const float*)d_in[25];

  char* w = (char*)d_ws;
  auto alloc = [&](size_t n) -> char* {
    char* p = w; w += (n + 255) & ~(size_t)255; return p;
  };
  u16*   Wpe  = (u16*)  alloc(2l * FD * K2 * 2);       // 32 MB
  u16*   Wpd  = (u16*)  alloc(2l * FD * K2 * 2);       // 32 MB
  u16*   xb   = (u16*)  alloc((long)T_ * BD * 2);      // 32 MB
  u16*   xd0  = (u16*)  alloc((long)BD * 2);
  u16*   H0e  = (u16*)  alloc(2l * BD * 2);
  u16*   h1e  = (u16*)  alloc(2l * BD * 2);
  u16*   h0d  = (u16*)  alloc(2l * BD * 2);
  u16*   yb   = (u16*)  alloc(2l * BD * 2);
  u16*   hd0i = (u16*)  alloc((long)BD * 2);
  u16*   hd1i = (u16*)  alloc((long)BD * 2);
  float* ce0  = (float*)alloc((long)BD * 4);
  float* ce1  = (float*)alloc((long)BD * 4);
  float* cd0  = (float*)alloc((long)BD * 4);
  float* cd1  = (float*)alloc((long)BD * 4);
  float* bp   = (float*)alloc(4l * FD * 4);
  float* vv   = (float*)alloc(8l * D_ * 4);
  float* uinv = (float*)alloc(64);
  float* vss  = (float*)alloc(256);
  float* sgp  = (float*)alloc(4096);
  float* rsig = (float*)alloc(64);
  unsigned* bar = (unsigned*)alloc(16384);

  hipMemsetAsync(bar, 0, 16384, stream);

  k_unorm<<<8,    256, 0, stream>>>(euih, euhh, duih, duhh, uinv);
  k_v    <<<32,   256, 0, stream>>>(eWih, eWhh, dWih, dWhh, euih, euhh, duih, duhh,
                                    uinv, vv, vss);
  k_sig  <<<512,  256, 0, stream>>>(eWih, eWhh, dWih, dWhh, vv, sgp);
  k_fin  <<<1,    64,  0, stream>>>(vss, sgp, rsig);
  k_pack <<<16384,256, 0, stream>>>(eWih, eWhh, dWih, dWhh, rsig, Wpe, Wpd);
  k_packb<<<64,   256, 0, stream>>>(eb, db, bp);
  k_xb   <<<4096, 512, 0, stream>>>(x, xb);
  k_xd0  <<<16,   512, 0, stream>>>(initial, xd0);

  float* out = (float*)d_out;
  float* muo = out + (long)B_ * T_ * D_;
  float* sgo = muo + 4l * B_ * G_;

  persist<<<NWG, 512, 0, stream>>>(Wpe, Wpd, bp, xb, xd0,
                                   H0e, h1e, h0d, yb,
                                   ce0, ce1, hd0i, hd1i, cd0, cd1,
                                   hmuW, hmub, hsgW, hsgb, houtW, houtb,
                                   cmuW, cmub, csgW, csgb, coutW, coutb,
                                   eps_h, eps_c, out, muo, sgo, bar);
}

// Round 7
// 8044.117 us; speedup vs baseline: 2.3469x; 2.3469x over previous
//
#include <hip/hip_runtime.h>

// LSTM-VAE  B=64 T=256 D=1024 L=2 G=128 — persistent kernel.
// h-exchange: write-through coherent stores (sc0 sc1) + NORMAL cached loads
// of NEVER-REUSED ring slots (256/phase) -> per-XCD L2 serves the broadcast
// with zero cache-maintenance in the hot loop. Fences only at phase edges.
#define B_  64
#define T_  256
#define D_  1024
#define G_  128
#define FD  4096   // 4*D
#define K2  2048   // D (ih) + D (hh)
#define BD  65536  // B_*D_
#define NWG 256

typedef unsigned short u16;
typedef __attribute__((ext_vector_type(8))) short frag8;  // 8 bf16
typedef __attribute__((ext_vector_type(4))) float f4;

__device__ __forceinline__ u16 f2b(float f) {
  unsigned u = __float_as_uint(f);
  u += 0x7fffu + ((u >> 16) & 1u);
  return (u16)(u >> 16);
}
__device__ __forceinline__ float b2f(u16 s) {
  return __uint_as_float(((unsigned)s) << 16);
}
__device__ __forceinline__ float sigm(float x) { return 1.0f / (1.0f + __expf(-x)); }

// write-through coherent store (lands at LLC once vmcnt drains; no dirty L2)
__device__ __forceinline__ void stcoh(unsigned* p, unsigned w) {
  asm volatile("global_store_dword %0, %1, off sc0 sc1"
               :: "v"(p), "v"(w) : "memory");
}

// ---------------- 2-level grid barrier, NO cache maintenance ----------------
// cnt: 64 counters, 128B apart (4 WGs each). rel: release word. ep: 1-based.
__device__ __forceinline__ void lightbar(unsigned* cnt, unsigned* rel,
                                         unsigned ep, int wg) {
  asm volatile("s_waitcnt vmcnt(0)" ::: "memory");   // drain sc0sc1 stores
  __syncthreads();
  const int tid = threadIdx.x;
  if (tid == 0)
    __hip_atomic_fetch_add(&cnt[(wg & 63) * 32], 1u, __ATOMIC_RELAXED,
                           __HIP_MEMORY_SCOPE_AGENT);
  if (wg == 0) {
    if (tid < 64) {
      while (__hip_atomic_load(&cnt[tid * 32], __ATOMIC_RELAXED,
                               __HIP_MEMORY_SCOPE_AGENT) < ep * 4u)
        __builtin_amdgcn_s_sleep(1);
    }
    __syncthreads();
    if (tid == 0)
      __hip_atomic_store(rel, ep, __ATOMIC_RELAXED, __HIP_MEMORY_SCOPE_AGENT);
  } else {
    if (tid == 0) {
      while (__hip_atomic_load(rel, __ATOMIC_RELAXED,
                               __HIP_MEMORY_SCOPE_AGENT) < ep)
        __builtin_amdgcn_s_sleep(1);
    }
  }
  __syncthreads();
}

// heavyweight barrier for phase transitions (dirty stores + cache reuse cross)
__device__ __forceinline__ void fencedbar(unsigned* cnt, unsigned* rel,
                                          unsigned ep, int wg) {
  __builtin_amdgcn_fence(__ATOMIC_RELEASE, "agent");   // wbl2
  lightbar(cnt, rel, ep, wg);
  __builtin_amdgcn_fence(__ATOMIC_ACQUIRE, "agent");   // inv
  __syncthreads();
}

// ---------------- weight slice load: 32 rows x 2048 bf16, XOR-swizzled ------
__device__ __forceinline__ void load_weights(const u16* __restrict__ Wg, char* wlds) {
  const int t  = threadIdx.x;
  const int r  = t >> 4;           // 0..31
  const int c0 = t & 15;
  const char* src = (const char*)(Wg + (long)r * K2);
  char* dstrow = wlds + (r << 12);
  const int swz = (r & 7) << 4;
  #pragma unroll
  for (int i = 0; i < 16; ++i) {
    const int cb = (c0 + (i << 4)) << 4;      // chunk byte offset
    frag8 v = *(const frag8*)(src + cb);
    *(frag8*)(dstrow + (cb ^ swz)) = v;
  }
  __syncthreads();
}

// ---------------- one LSTM cell for this WG's 8 units -----------------------
// A0 (k<1024), A1 (k>=1024); both NORMAL cached loads (ring slots are fresh
// addresses -> guaranteed L2 miss -> LLC-fresh data, then L2-shared on XCD).
__device__ __forceinline__ void cell(
    const u16* __restrict__ A0, const u16* __restrict__ A1,
    const char* wlds, float* gl,
    float& c_reg, const f4& bias, int ug0,
    u16* __restrict__ hout, float* __restrict__ fout, long fstride)
{
  const int tid = threadIdx.x;
  const int lane = tid & 63, wv = tid >> 6;
  const int mt = wv & 3, kh = wv >> 2;
  const int l15 = lane & 15, lgr = lane >> 4;

  f4 acc0 = (f4){0.f,0.f,0.f,0.f}, acc1 = (f4){0.f,0.f,0.f,0.f};
  const u16* Ab = kh ? A1 : A0;
  if (Ab) {
    const u16* ap = Ab + (mt * 16 + l15) * 1024 + lgr * 8;
    const int kbyte0 = (kh << 11) + (lgr << 4);
    const int swz = (l15 & 7) << 4;
    const char* w0r = wlds + ((long)l15 << 12);
    const char* w1r = wlds + ((long)(16 + l15) << 12);
    #pragma unroll 8
    for (int kk = 0; kk < 32; ++kk) {
      frag8 af = *(const frag8*)(ap + kk * 32);
      const int kb = (kbyte0 + (kk << 6)) ^ swz;
      frag8 b0 = *(const frag8*)(w0r + kb);
      frag8 b1 = *(const frag8*)(w1r + kb);
      acc0 = __builtin_amdgcn_mfma_f32_16x16x32_bf16(af, b0, acc0, 0, 0, 0);
      acc1 = __builtin_amdgcn_mfma_f32_16x16x32_bf16(af, b1, acc1, 0, 0, 0);
    }
  }
  float* g = gl + kh * (64 * 32);
  const int orow = mt * 16 + lgr * 4;
  #pragma unroll
  for (int r = 0; r < 4; ++r) {
    g[(orow + r) * 32 + l15]      = acc0[r];
    g[(orow + r) * 32 + 16 + l15] = acc1[r];
  }
  __syncthreads();

  const int row = tid >> 3, ul = tid & 7;
  f4 p0 = *(const f4*)(gl + row * 32 + ul * 4);
  f4 p1 = *(const f4*)(gl + 64 * 32 + row * 32 + ul * 4);
  float iv = p0.x + p1.x + bias.x;
  float fv = p0.y + p1.y + bias.y;
  float gv = p0.z + p1.z + bias.z;
  float ov = p0.w + p1.w + bias.w;
  float cn = sigm(fv) * c_reg + sigm(iv) * tanhf(gv);
  float hh = sigm(ov) * tanhf(cn);
  c_reg = cn;
  // coherent paired u16 store (even lane stores the u32 word)
  unsigned hv = (unsigned)f2b(hh);
  unsigned other = __shfl_xor(hv, 1);
  if (!(ul & 1)) {
    unsigned word = hv | (other << 16);
    stcoh((unsigned*)(hout + row * 1024 + ug0 + ul), word);
  }
  if (fout) fout[(long)row * fstride + ug0 + ul] = hh;
  __syncthreads();   // protect gl for next cell
}

// ---------------- VAE head, one (s,l,b) per WG ------------------------------
__device__ __forceinline__ void vae_wg(
    int bid, char* scr,
    const u16* h0f, const u16* h1f, const float* c0f, const float* c1f,
    const float* hmuW, const float* hmub, const float* hsgW, const float* hsgb,
    const float* houtW, const float* houtb,
    const float* cmuW, const float* cmub, const float* csgW, const float* csgb,
    const float* coutW, const float* coutb,
    const float* eps_h, const float* eps_c,
    float* muo, float* sgo, u16* hd0, u16* hd1, float* cd0, float* cd1)
{
  float* hrow = (float*)scr;
  float* muv  = hrow + 1024;
  float* sgv  = muv + 128;
  float* zz   = sgv + 128;
  const int tid = threadIdx.x;
  const int b = bid & 63, l = (bid >> 6) & 1, s = bid >> 7;

  if (s == 0) {
    const u16* h = (l ? h1f : h0f) + b * D_;
    for (int i = tid; i < D_; i += 512) hrow[i] = b2f(h[i]);
  } else {
    const float* c = (l ? c1f : c0f) + b * D_;
    for (int i = tid; i < D_; i += 512) hrow[i] = c[i];
  }
  __syncthreads();

  const float* muW = (s ? cmuW : hmuW) + (long)l * G_ * D_;
  const float* sgW = (s ? csgW : hsgW) + (long)l * G_ * D_;
  const float* mub = (s ? cmub : hmub) + l * G_;
  const float* sgb = (s ? csgb : hsgb) + l * G_;
  const int wv = tid >> 6, lane = tid & 63;
  for (int oi = wv; oi < 2 * G_; oi += 8) {
    const int g = (oi < G_) ? oi : oi - G_;
    const float* Wr = ((oi < G_) ? muW : sgW) + (long)g * D_;
    float d = 0.f;
    for (int j = lane; j < D_; j += 64) d += Wr[j] * hrow[j];
    for (int off = 1; off < 64; off <<= 1) d += __shfl_xor(d, off);
    if (lane == 0) {
      if (oi < G_) muv[g] = d + mub[g]; else sgv[g] = d + sgb[g];
    }
  }
  __syncthreads();
  if (tid < G_) {
    const int g = tid;
    const float mu = muv[g], sg = sgv[g];
    const float* ep = (s ? eps_c : eps_h) + ((long)l * B_ + b) * G_;
    zz[g] = mu + ep[g] * __expf(sg);
    muo[(long)bid * G_ + g] = mu;
    sgo[(long)bid * G_ + g] = sg;
  }
  __syncthreads();
  const float* oW  = (s ? coutW : houtW) + (long)l * D_ * G_;
  const float* obv = (s ? coutb : houtb) + l * D_;
  for (int i = 0; i < 2; ++i) {
    const int dd = i * 512 + tid;
    float acc = obv[dd];
    const float* Wr = oW + (long)dd * G_;
    #pragma unroll 4
    for (int g = 0; g < G_; ++g) acc += zz[g] * Wr[g];
    if (s == 0) { (l ? hd1 : hd0)[b * D_ + dd] = f2b(acc); }
    else        { (l ? cd1 : cd0)[b * D_ + dd] = acc; }
  }
  __syncthreads();
}

// ---------------- the persistent kernel -------------------------------------
// ring0 / ring1: 256 slots x [64][1024] bf16. Encoder: ring0 = h0[t],
// ring1 = h1[t]. Decoder (after fencedbar invalidates): ring0 = h0d[t],
// ring1 = y[t]. Every slot written exactly once per phase -> always-fresh
// addresses for consumer L2s.
__global__ __launch_bounds__(512, 1)
void persist(const u16* __restrict__ Wpe, const u16* __restrict__ Wpd,
             const float* __restrict__ bp,
             const u16* __restrict__ xb, const u16* __restrict__ xd0,
             u16* ring0, u16* ring1,
             float* ce0, float* ce1,
             u16* hd0i, u16* hd1i, float* cd0, float* cd1,
             const float* hmuW, const float* hmub, const float* hsgW, const float* hsgb,
             const float* houtW, const float* houtb,
             const float* cmuW, const float* cmub, const float* csgW, const float* csgb,
             const float* coutW, const float* coutb,
             const float* eps_h, const float* eps_c,
             float* out, float* muo, float* sgo, unsigned* bar)
{
  __shared__ __align__(16) char smem[147456];   // 128K weights + 16K scratch
  char*  wlds = smem;
  float* gl   = (float*)(smem + 131072);

  unsigned* cnt = bar;          // 64 counters * 32 u32 stride
  unsigned* rel = bar + 2048;

  const int wg  = blockIdx.x;
  const bool isL0 = (wg < 128);
  const int wgL = wg & 127;
  const int ug0 = wgL * 8;
  const int tid = threadIdx.x;
  unsigned ep = 0;

  // ---- encoder phase ----
  load_weights(Wpe + (isL0 ? 0l : (long)FD * K2) + (long)wgL * 32 * K2, wlds);
  f4 bias = *(const f4*)(bp + (isL0 ? 0 : FD) + (ug0 + (tid & 7)) * 4);
  float c_reg = 0.f;

  for (int s = 0; s <= 256; ++s) {
    if (isL0) {
      if (s < 256)
        cell(xb + (long)s * BD,
             s ? (ring0 + (long)(s - 1) * BD) : nullptr,
             wlds, gl, c_reg, bias, ug0,
             ring0 + (long)s * BD, nullptr, 0);
    } else {
      if (s >= 1)
        cell(ring0 + (long)(s - 1) * BD,
             (s >= 2) ? (ring1 + (long)(s - 2) * BD) : nullptr,
             wlds, gl, c_reg, bias, ug0,
             ring1 + (long)(s - 1) * BD, nullptr, 0);
    }
    lightbar(cnt, rel, ++ep, wg);
  }
  // publish final c (normal stores; fenced barrier follows)
  {
    const int row = tid >> 3, ul = tid & 7;
    (isL0 ? ce0 : ce1)[row * D_ + ug0 + ul] = c_reg;
  }
  fencedbar(cnt, rel, ++ep, wg);

  // ---- VAE ----
  vae_wg(wg, (char*)gl,
         ring0 + 255l * BD, ring1 + 255l * BD, ce0, ce1,
         hmuW, hmub, hsgW, hsgb, houtW, houtb,
         cmuW, cmub, csgW, csgb, coutW, coutb,
         eps_h, eps_c, muo, sgo, hd0i, hd1i, cd0, cd1);
  fencedbar(cnt, rel, ++ep, wg);   // also invalidates encoder-phase ring lines

  // ---- decoder phase ----
  load_weights(Wpd + (isL0 ? 0l : (long)FD * K2) + (long)wgL * 32 * K2, wlds);
  bias = *(const f4*)(bp + 2 * FD + (isL0 ? 0 : FD) + (ug0 + (tid & 7)) * 4);
  {
    const int row = tid >> 3, ul = tid & 7;
    c_reg = (isL0 ? cd0 : cd1)[row * D_ + ug0 + ul];
  }
  lightbar(cnt, rel, ++ep, wg);

  for (int t = 0; t < T_; ++t) {
    if (isL0)
      cell(t ? (ring1 + (long)(t - 1) * BD) : xd0,
           t ? (ring0 + (long)(t - 1) * BD) : hd0i,
           wlds, gl, c_reg, bias, ug0,
           ring0 + (long)t * BD, nullptr, 0);
    lightbar(cnt, rel, ++ep, wg);
    if (!isL0)
      cell(ring0 + (long)t * BD,
           t ? (ring1 + (long)(t - 1) * BD) : hd1i,
           wlds, gl, c_reg, bias, ug0,
           ring1 + (long)t * BD, out + (long)t * D_, (long)T_ * D_);
    lightbar(cnt, rel, ++ep, wg);
  }
}

// ---------------------------------------------------------------------------
// Spectral norm prepass (unchanged, verified)
// ---------------------------------------------------------------------------
__device__ __forceinline__ const float* selW(int m, const float* a, const float* b,
                                             const float* c, const float* d) {
  const float* W;
  switch (m >> 1) { case 0: W = a; break; case 1: W = b; break;
                    case 2: W = c; break; default: W = d; }
  return W + (long)(m & 1) * FD * D_;
}
__device__ __forceinline__ const float* selU(int m, const float* a, const float* b,
                                             const float* c, const float* d) {
  const float* u;
  switch (m >> 1) { case 0: u = a; break; case 1: u = b; break;
                    case 2: u = c; break; default: u = d; }
  return u + (m & 1) * FD;
}

__global__ __launch_bounds__(256)
void k_unorm(const float* euih, const float* euhh, const float* duih, const float* duhh,
             float* uinv)
{
  const int m = blockIdx.x;
  const float* u = selU(m, euih, euhh, duih, duhh);
  float s = 0.f;
  for (int i = threadIdx.x; i < FD; i += 256) { float v = u[i]; s += v * v; }
  __shared__ float red[4];
  for (int off = 1; off < 64; off <<= 1) s += __shfl_xor(s, off);
  if ((threadIdx.x & 63) == 0) red[threadIdx.x >> 6] = s;
  __syncthreads();
  if (threadIdx.x == 0)
    uinv[m] = 1.0f / (sqrtf(red[0] + red[1] + red[2] + red[3]) + 1e-12f);
}

__global__ __launch_bounds__(256)
void k_v(const float* eWih, const float* eWhh, const float* dWih, const float* dWhh,
         const float* euih, const float* euhh, const float* duih, const float* duhh,
         const float* uinv, float* v, float* vss)
{
  __shared__ float us[FD];
  __shared__ float red[4];
  const int m = blockIdx.x >> 2, cb = blockIdx.x & 3;
  const float* W = selW(m, eWih, eWhh, dWih, dWhh);
  const float* u = selU(m, euih, euhh, duih, duhh);
  for (int i = threadIdx.x; i < FD; i += 256) us[i] = u[i];
  __syncthreads();
  const int j = cb * 256 + threadIdx.x;
  float acc = 0.f;
  for (int i = 0; i < FD; ++i) acc += W[(long)i * D_ + j] * us[i];
  acc *= uinv[m];
  v[m * D_ + j] = acc;
  float s = acc * acc;
  for (int off = 1; off < 64; off <<= 1) s += __shfl_xor(s, off);
  if ((threadIdx.x & 63) == 0) red[threadIdx.x >> 6] = s;
  __syncthreads();
  if (threadIdx.x == 0) vss[blockIdx.x] = red[0] + red[1] + red[2] + red[3];
}

__global__ __launch_bounds__(256)
void k_sig(const float* eWih, const float* eWhh, const float* dWih, const float* dWhh,
           const float* v, float* sgp)
{
  __shared__ float vl[D_];
  __shared__ float red[4];
  const int m = blockIdx.x >> 6, rb = blockIdx.x & 63;
  const float* W = selW(m, eWih, eWhh, dWih, dWhh);
  for (int i = threadIdx.x; i < D_; i += 256) vl[i] = v[m * D_ + i];
  __syncthreads();
  const int wv = threadIdx.x >> 6, lane = threadIdx.x & 63;
  float ssq = 0.f;
  for (int rr = 0; rr < 16; ++rr) {
    const int r = rb * 64 + wv * 16 + rr;
    const float* Wr = W + (long)r * D_;
    float d = 0.f;
    for (int j = lane; j < D_; j += 64) d += Wr[j] * vl[j];
    for (int off = 1; off < 64; off <<= 1) d += __shfl_xor(d, off);
    ssq += d * d;
  }
  if (lane == 0) red[wv] = ssq;
  __syncthreads();
  if (threadIdx.x == 0) sgp[blockIdx.x] = red[0] + red[1] + red[2] + red[3];
}

__global__ void k_fin(const float* vss, const float* sgp, float* rsig)
{
  const int m = threadIdx.x;
  if (m < 8) {
    float vn = sqrtf(vss[m * 4] + vss[m * 4 + 1] + vss[m * 4 + 2] + vss[m * 4 + 3]);
    float s2 = 0.f;
    for (int i = 0; i < 64; ++i) s2 += sgp[m * 64 + i];
    rsig[m] = (vn + 1e-12f) / sqrtf(s2);   // 1/sigma
  }
}

__global__ __launch_bounds__(256)
void k_pack(const float* eWih, const float* eWhh, const float* dWih, const float* dWhh,
            const float* rsig, u16* Wpe, u16* Wpd)
{
  const long idx = (long)blockIdx.x * 256 + threadIdx.x;
  const int k8   = (int)(idx & 255);
  const int np   = (int)((idx >> 8) & 4095);
  const int pair = (int)(idx >> 20);
  const int l = pair & 1, ed = pair >> 1;
  const int u = np >> 2, g = np & 3;
  const int srow = g * D_ + u;
  const int k = k8 * 8;
  const float* src; float sc;
  if (k < D_) {
    const float* Wih = ed ? dWih : eWih;
    src = Wih + ((long)(l * FD + srow)) * D_ + k;
    sc  = rsig[ed ? 4 + l : l];
  } else {
    const float* Whh = ed ? dWhh : eWhh;
    src = Whh + ((long)(l * FD + srow)) * D_ + (k - D_);
    sc  = rsig[ed ? 6 + l : 2 + l];
  }
  f4 a = *(const f4*)src;
  f4 b = *(const f4*)(src + 4);
  frag8 o;
  o[0] = (short)f2b(a.x * sc); o[1] = (short)f2b(a.y * sc);
  o[2] = (short)f2b(a.z * sc); o[3] = (short)f2b(a.w * sc);
  o[4] = (short)f2b(b.x * sc); o[5] = (short)f2b(b.y * sc);
  o[6] = (short)f2b(b.z * sc); o[7] = (short)f2b(b.w * sc);
  u16* dst = (ed ? Wpd : Wpe) + ((long)(l * FD + np)) * K2 + k;
  *(frag8*)dst = o;
}

__global__ void k_packb(const float* eb, const float* db, float* bp)
{
  const int idx = blockIdx.x * 256 + threadIdx.x;   // 4*4096
  const int j = idx & 4095, pair = idx >> 12;
  const int l = pair & 1, ed = pair >> 1;
  const float* b = (ed ? db : eb) + l * FD;
  bp[pair * FD + j] = b[(j & 3) * D_ + (j >> 2)];
}

// x [B,T,D] f32 -> xb [T][B][D] bf16
__global__ __launch_bounds__(512)
void k_xb(const float* __restrict__ x, u16* __restrict__ xb)
{
  const long i8 = ((long)blockIdx.x * 512 + threadIdx.x) * 8;
  const int d  = (int)(i8 & 1023);
  const int bt = (int)(i8 >> 10);
  const int b = bt & 63, t = bt >> 6;
  const float* src = x + ((long)b * T_ + t) * D_ + d;
  f4 a = *(const f4*)src;
  f4 c = *(const f4*)(src + 4);
  frag8 o;
  o[0] = (short)f2b(a.x); o[1] = (short)f2b(a.y);
  o[2] = (short)f2b(a.z); o[3] = (short)f2b(a.w);
  o[4] = (short)f2b(c.x); o[5] = (short)f2b(c.y);
  o[6] = (short)f2b(c.z); o[7] = (short)f2b(c.w);
  *(frag8*)(xb + i8) = o;
}

__global__ __launch_bounds__(512)
void k_xd0(const float* __restrict__ initial, u16* __restrict__ xd0)
{
  const int i8 = (blockIdx.x * 512 + threadIdx.x) * 8;   // < 65536
  const int d = i8 & 1023;
  f4 a = *(const f4*)(initial + d);
  f4 c = *(const f4*)(initial + d + 4);
  frag8 o;
  o[0] = (short)f2b(a.x); o[1] = (short)f2b(a.y);
  o[2] = (short)f2b(a.z); o[3] = (short)f2b(a.w);
  o[4] = (short)f2b(c.x); o[5] = (short)f2b(c.y);
  o[6] = (short)f2b(c.z); o[7] = (short)f2b(c.w);
  *(frag8*)(xd0 + i8) = o;
}

// ---------------------------------------------------------------------------
extern "C" void kernel_launch(void* const* d_in, const int* in_sizes, int n_in,
                              void* d_out, int out_size, void* d_ws, size_t ws_size,
                              hipStream_t stream)
{
  const float* x       = (const float*)d_in[0];
  const float* initial = (const float*)d_in[1];
  const float* eWih    = (const float*)d_in[2];
  const float* eWhh    = (const float*)d_in[3];
  const float* eb      = (const float*)d_in[4];
  const float* euih    = (const float*)d_in[5];
  const float* euhh    = (const float*)d_in[6];
  const float* dWih    = (const float*)d_in[7];
  const float* dWhh    = (const float*)d_in[8];
  const float* db      = (const float*)d_in[9];
  const float* duih    = (const float*)d_in[10];
  const float* duhh    = (const float*)d_in[11];
  const float* hmuW    = (const float*)d_in[12];
  const float* hmub    = (const float*)d_in[13];
  const float* hsgW    = (const float*)d_in[14];
  const float* hsgb    = (const float*)d_in[15];
  const float* houtW   = (const float*)d_in[16];
  const float* houtb   = (const float*)d_in[17];
  const float* cmuW    = (const float*)d_in[18];
  const float* cmub    = (const float*)d_in[19];
  const float* csgW    = (const float*)d_in[20];
  const float* csgb    = (const float*)d_in[21];
  const float* coutW   = (const float*)d_in[22];
  const float* coutb   = (const float*)d_in[23];
  const float* eps_h   = (const float*)d_in[24];
  const float* eps_c   = (const float*)d_in[25];

  char* w = (char*)d_ws;
  auto alloc = [&](size_t n) -> char* {
    char* p = w; w += (n + 255) & ~(size_t)255; return p;
  };
  u16*   Wpe   = (u16*)  alloc(2l * FD * K2 * 2);       // 32 MB
  u16*   Wpd   = (u16*)  alloc(2l * FD * K2 * 2);       // 32 MB
  u16*   xb    = (u16*)  alloc((long)T_ * BD * 2);      // 32 MB
  u16*   ring0 = (u16*)  alloc((long)T_ * BD * 2);      // 32 MB
  u16*   ring1 = (u16*)  alloc((long)T_ * BD * 2);      // 32 MB
  u16*   xd0   = (u16*)  alloc((long)BD * 2);
  u16*   hd0i  = (u16*)  alloc((long)BD * 2);
  u16*   hd1i  = (u16*)  alloc((long)BD * 2);
  float* ce0   = (float*)alloc((long)BD * 4);
  float* ce1   = (float*)alloc((long)BD * 4);
  float* cd0   = (float*)alloc((long)BD * 4);
  float* cd1   = (float*)alloc((long)BD * 4);
  float* bp    = (float*)alloc(4l * FD * 4);
  float* vv    = (float*)alloc(8l * D_ * 4);
  float* uinv  = (float*)alloc(64);
  float* vss   = (float*)alloc(256);
  float* sgp   = (float*)alloc(4096);
  float* rsig  = (float*)alloc(64);
  unsigned* bar = (unsigned*)alloc(16384);

  hipMemsetAsync(bar, 0, 16384, stream);

  k_unorm<<<8,    256, 0, stream>>>(euih, euhh, duih, duhh, uinv);
  k_v    <<<32,   256, 0, stream>>>(eWih, eWhh, dWih, dWhh, euih, euhh, duih, duhh,
                                    uinv, vv, vss);
  k_sig  <<<512,  256, 0, stream>>>(eWih, eWhh, dWih, dWhh, vv, sgp);
  k_fin  <<<1,    64,  0, stream>>>(vss, sgp, rsig);
  k_pack <<<16384,256, 0, stream>>>(eWih, eWhh, dWih, dWhh, rsig, Wpe, Wpd);
  k_packb<<<64,   256, 0, stream>>>(eb, db, bp);
  k_xb   <<<4096, 512, 0, stream>>>(x, xb);
  k_xd0  <<<16,   512, 0, stream>>>(initial, xd0);

  float* out = (float*)d_out;
  float* muo = out + (long)B_ * T_ * D_;
  float* sgo = muo + 4l * B_ * G_;

  persist<<<NWG, 512, 0, stream>>>(Wpe, Wpd, bp, xb, xd0,
                                   ring0, ring1,
                                   ce0, ce1, hd0i, hd1i, cd0, cd1,
                                   hmuW, hmub, hsgW, hsgb, houtW, houtb,
                                   cmuW, cmub, csgW, csgb, coutW, coutb,
                                   eps_h, eps_c, out, muo, sgo, bar);
}

// Round 8
// 7073.210 us; speedup vs baseline: 2.6690x; 1.1373x over previous
//
#include <hip/hip_runtime.h>

// LSTM-VAE  B=64 T=256 D=1024 L=2 G=128 — persistent kernel, barrier-free:
// producer/consumer group signals (16 spread LLC counter lines per group,
// direct wave-polling), write-through coherent h-stores, never-reused ring
// slots, fences only at the two phase edges.
#define B_  64
#define T_  256
#define D_  1024
#define G_  128
#define FD  4096   // 4*D
#define K2  2048   // D (ih) + D (hh)
#define BD  65536  // B_*D_
#define NWG 256
#define CL  128    // u32 stride between counter lines (512 B)

typedef unsigned short u16;
typedef __attribute__((ext_vector_type(8))) short frag8;  // 8 bf16
typedef __attribute__((ext_vector_type(4))) float f4;

__device__ __forceinline__ u16 f2b(float f) {
  unsigned u = __float_as_uint(f);
  u += 0x7fffu + ((u >> 16) & 1u);
  return (u16)(u >> 16);
}
__device__ __forceinline__ float b2f(u16 s) {
  return __uint_as_float(((unsigned)s) << 16);
}
__device__ __forceinline__ float sigm(float x) { return 1.0f / (1.0f + __expf(-x)); }

// write-through coherent store (lands at LLC once vmcnt drains; no dirty L2)
__device__ __forceinline__ void stcoh(unsigned* p, unsigned w) {
  asm volatile("global_store_dword %0, %1, off sc0 sc1"
               :: "v"(p), "v"(w) : "memory");
}

// ---------------- group-signal primitives -----------------------------------
// wait: lanes 0..15 of the calling wave poll 16 counter lines until each
// reaches tgt (= 8*epoch for a 128-WG group, 16*epoch for full grid).
__device__ __forceinline__ void wave_wait16(const unsigned* cnt, unsigned tgt) {
  const int l = threadIdx.x & 63;
  if (l < 16) {
    while (__hip_atomic_load(&cnt[l * CL], __ATOMIC_RELAXED,
                             __HIP_MEMORY_SCOPE_AGENT) < tgt)
      __builtin_amdgcn_s_sleep(2);
  }
  asm volatile("" ::: "memory");   // no load hoisting above the poll
}

// arrive: drain this WG's (coherent) stores, then one atomic add.
__device__ __forceinline__ void wg_arrive(unsigned* cnt, int wg) {
  asm volatile("s_waitcnt vmcnt(0)" ::: "memory");
  __syncthreads();
  if (threadIdx.x == 0)
    __hip_atomic_fetch_add(&cnt[(wg & 15) * CL], 1u, __ATOMIC_RELAXED,
                           __HIP_MEMORY_SCOPE_AGENT);
}

// full-grid sync (phase edges only); fenced = release/acquire cache ops
__device__ __forceinline__ void fullsync(unsigned* g, unsigned ep, int wg,
                                         bool fenced) {
  if (fenced) __builtin_amdgcn_fence(__ATOMIC_RELEASE, "agent");
  wg_arrive(g, wg);
  wave_wait16(g, ep * 16u);
  __syncthreads();
  if (fenced) {
    __builtin_amdgcn_fence(__ATOMIC_ACQUIRE, "agent");
    __syncthreads();
  }
}

// ---------------- weight slice load: 32 rows x 2048 bf16, XOR-swizzled ------
__device__ __forceinline__ void load_weights(const u16* __restrict__ Wg, char* wlds) {
  const int t  = threadIdx.x;
  const int r  = t >> 4;           // 0..31
  const int c0 = t & 15;
  const char* src = (const char*)(Wg + (long)r * K2);
  char* dstrow = wlds + (r << 12);
  const int swz = (r & 7) << 4;
  #pragma unroll
  for (int i = 0; i < 16; ++i) {
    const int cb = (c0 + (i << 4)) << 4;      // chunk byte offset
    frag8 v = *(const frag8*)(src + cb);
    *(frag8*)(dstrow + (cb ^ swz)) = v;
  }
  __syncthreads();
}

// ---------------- one LSTM cell with per-wave dependency waits --------------
// A0 (k<1024) waits on c0p>=t0; A1 (k>=1024) waits on c1p>=t1 (null = ready).
__device__ __forceinline__ void cellw(
    const u16* __restrict__ A0, const unsigned* c0p, unsigned t0,
    const u16* __restrict__ A1, const unsigned* c1p, unsigned t1,
    const char* wlds, float* gl,
    float& c_reg, const f4& bias, int ug0,
    u16* __restrict__ hout, float* __restrict__ fout, long fstride)
{
  const int tid = threadIdx.x;
  const int lane = tid & 63, wv = tid >> 6;
  const int mt = wv & 3, kh = wv >> 2;
  const int l15 = lane & 15, lgr = lane >> 4;

  f4 acc0 = (f4){0.f,0.f,0.f,0.f}, acc1 = (f4){0.f,0.f,0.f,0.f};
  const u16* Ab = kh ? A1 : A0;
  const unsigned* cp = kh ? c1p : c0p;
  const unsigned tg  = kh ? t1 : t0;
  if (Ab) {
    if (cp) wave_wait16(cp, tg);           // only the dependent waves poll
    const u16* ap = Ab + (mt * 16 + l15) * 1024 + lgr * 8;
    const int kbyte0 = (kh << 11) + (lgr << 4);
    const int swz = (l15 & 7) << 4;
    const char* w0r = wlds + ((long)l15 << 12);
    const char* w1r = wlds + ((long)(16 + l15) << 12);
    #pragma unroll 8
    for (int kk = 0; kk < 32; ++kk) {
      frag8 af = *(const frag8*)(ap + kk * 32);
      const int kb = (kbyte0 + (kk << 6)) ^ swz;
      frag8 b0 = *(const frag8*)(w0r + kb);
      frag8 b1 = *(const frag8*)(w1r + kb);
      acc0 = __builtin_amdgcn_mfma_f32_16x16x32_bf16(af, b0, acc0, 0, 0, 0);
      acc1 = __builtin_amdgcn_mfma_f32_16x16x32_bf16(af, b1, acc1, 0, 0, 0);
    }
  }
  float* g = gl + kh * (64 * 32);
  const int orow = mt * 16 + lgr * 4;
  #pragma unroll
  for (int r = 0; r < 4; ++r) {
    g[(orow + r) * 32 + l15]      = acc0[r];
    g[(orow + r) * 32 + 16 + l15] = acc1[r];
  }
  __syncthreads();

  const int row = tid >> 3, ul = tid & 7;
  f4 p0 = *(const f4*)(gl + row * 32 + ul * 4);
  f4 p1 = *(const f4*)(gl + 64 * 32 + row * 32 + ul * 4);
  float iv = p0.x + p1.x + bias.x;
  float fv = p0.y + p1.y + bias.y;
  float gv = p0.z + p1.z + bias.z;
  float ov = p0.w + p1.w + bias.w;
  float cn = sigm(fv) * c_reg + sigm(iv) * tanhf(gv);
  float hh = sigm(ov) * tanhf(cn);
  c_reg = cn;
  unsigned hv = (unsigned)f2b(hh);
  unsigned other = __shfl_xor(hv, 1);
  if (!(ul & 1)) {
    unsigned word = hv | (other << 16);
    stcoh((unsigned*)(hout + row * 1024 + ug0 + ul), word);
  }
  if (fout) fout[(long)row * fstride + ug0 + ul] = hh;
  // NOTE: gl WAR protection comes from wg_arrive()'s __syncthreads.
}

// ---------------- VAE head, one (s,l,b) per WG ------------------------------
__device__ __forceinline__ void vae_wg(
    int bid, char* scr,
    const u16* h0f, const u16* h1f, const float* c0f, const float* c1f,
    const float* hmuW, const float* hmub, const float* hsgW, const float* hsgb,
    const float* houtW, const float* houtb,
    const float* cmuW, const float* cmub, const float* csgW, const float* csgb,
    const float* coutW, const float* coutb,
    const float* eps_h, const float* eps_c,
    float* muo, float* sgo, u16* hd0, u16* hd1, float* cd0, float* cd1)
{
  float* hrow = (float*)scr;
  float* muv  = hrow + 1024;
  float* sgv  = muv + 128;
  float* zz   = sgv + 128;
  const int tid = threadIdx.x;
  const int b = bid & 63, l = (bid >> 6) & 1, s = bid >> 7;

  if (s == 0) {
    const u16* h = (l ? h1f : h0f) + b * D_;
    for (int i = tid; i < D_; i += 512) hrow[i] = b2f(h[i]);
  } else {
    const float* c = (l ? c1f : c0f) + b * D_;
    for (int i = tid; i < D_; i += 512) hrow[i] = c[i];
  }
  __syncthreads();

  const float* muW = (s ? cmuW : hmuW) + (long)l * G_ * D_;
  const float* sgW = (s ? csgW : hsgW) + (long)l * G_ * D_;
  const float* mub = (s ? cmub : hmub) + l * G_;
  const float* sgb = (s ? csgb : hsgb) + l * G_;
  const int wv = tid >> 6, lane = tid & 63;
  for (int oi = wv; oi < 2 * G_; oi += 8) {
    const int g = (oi < G_) ? oi : oi - G_;
    const float* Wr = ((oi < G_) ? muW : sgW) + (long)g * D_;
    float d = 0.f;
    for (int j = lane; j < D_; j += 64) d += Wr[j] * hrow[j];
    for (int off = 1; off < 64; off <<= 1) d += __shfl_xor(d, off);
    if (lane == 0) {
      if (oi < G_) muv[g] = d + mub[g]; else sgv[g] = d + sgb[g];
    }
  }
  __syncthreads();
  if (tid < G_) {
    const int g = tid;
    const float mu = muv[g], sg = sgv[g];
    const float* ep = (s ? eps_c : eps_h) + ((long)l * B_ + b) * G_;
    zz[g] = mu + ep[g] * __expf(sg);
    muo[(long)bid * G_ + g] = mu;
    sgo[(long)bid * G_ + g] = sg;
  }
  __syncthreads();
  const float* oW  = (s ? coutW : houtW) + (long)l * D_ * G_;
  const float* obv = (s ? coutb : houtb) + l * D_;
  for (int i = 0; i < 2; ++i) {
    const int dd = i * 512 + tid;
    float acc = obv[dd];
    const float* Wr = oW + (long)dd * G_;
    #pragma unroll 4
    for (int g = 0; g < G_; ++g) acc += zz[g] * Wr[g];
    if (s == 0) { (l ? hd1 : hd0)[b * D_ + dd] = f2b(acc); }
    else        { (l ? cd1 : cd0)[b * D_ + dd] = acc; }
  }
  __syncthreads();
}

// ---------------- the persistent kernel -------------------------------------
// Signals: acnt/bcnt = encoder L0/L1 step arrivals, ccnt/dcnt = decoder L0/L1,
// gcnt = phase-edge full syncs. 128-WG group => per-line target 8*epoch.
__global__ __launch_bounds__(512, 1)
void persist(const u16* __restrict__ Wpe, const u16* __restrict__ Wpd,
             const float* __restrict__ bp,
             const u16* __restrict__ xb, const u16* __restrict__ xd0,
             u16* ring0, u16* ring1,
             float* ce0, float* ce1,
             u16* hd0i, u16* hd1i, float* cd0, float* cd1,
             const float* hmuW, const float* hmub, const float* hsgW, const float* hsgb,
             const float* houtW, const float* houtb,
             const float* cmuW, const float* cmub, const float* csgW, const float* csgb,
             const float* coutW, const float* coutb,
             const float* eps_h, const float* eps_c,
             float* out, float* muo, float* sgo, unsigned* bar)
{
  __shared__ __align__(16) char smem[147456];   // 128K weights + 16K scratch
  char*  wlds = smem;
  float* gl   = (float*)(smem + 131072);

  unsigned* gcnt = bar;
  unsigned* acnt = bar + 2048;
  unsigned* bcnt = bar + 4096;
  unsigned* ccnt = bar + 6144;
  unsigned* dcnt = bar + 8192;

  const int wg  = blockIdx.x;
  const bool isL0 = (wg < 128);
  const int wgL = wg & 127;
  const int ug0 = wgL * 8;
  const int tid = threadIdx.x;

  // ---- encoder phase (signal-driven, no grid barriers) ----
  load_weights(Wpe + (isL0 ? 0l : (long)FD * K2) + (long)wgL * 32 * K2, wlds);
  f4 bias = *(const f4*)(bp + (isL0 ? 0 : FD) + (ug0 + (tid & 7)) * 4);
  float c_reg = 0.f;

  if (isL0) {
    for (int s = 0; s < T_; ++s) {
      cellw(xb + (long)s * BD, nullptr, 0,
            s ? (ring0 + (long)(s - 1) * BD) : nullptr,
            s ? acnt : nullptr, 8u * (unsigned)s,
            wlds, gl, c_reg, bias, ug0,
            ring0 + (long)s * BD, nullptr, 0);
      wg_arrive(acnt, wg);
    }
  } else {
    for (int t = 0; t < T_; ++t) {
      cellw(ring0 + (long)t * BD, acnt, 8u * (unsigned)(t + 1),
            t ? (ring1 + (long)(t - 1) * BD) : nullptr,
            t ? bcnt : nullptr, 8u * (unsigned)t,
            wlds, gl, c_reg, bias, ug0,
            ring1 + (long)t * BD, nullptr, 0);
      wg_arrive(bcnt, wg);
    }
  }
  // publish final c (normal stores; fenced sync follows)
  {
    const int row = tid >> 3, ul = tid & 7;
    (isL0 ? ce0 : ce1)[row * D_ + ug0 + ul] = c_reg;
  }
  fullsync(gcnt, 1, wg, true);

  // ---- VAE ----
  vae_wg(wg, (char*)gl,
         ring0 + 255l * BD, ring1 + 255l * BD, ce0, ce1,
         hmuW, hmub, hsgW, hsgb, houtW, houtb,
         cmuW, cmub, csgW, csgb, coutW, coutb,
         eps_h, eps_c, muo, sgo, hd0i, hd1i, cd0, cd1);
  fullsync(gcnt, 2, wg, true);   // also invalidates encoder-era ring lines

  // ---- decoder phase (signal-driven, 2 handoffs/step) ----
  load_weights(Wpd + (isL0 ? 0l : (long)FD * K2) + (long)wgL * 32 * K2, wlds);
  bias = *(const f4*)(bp + 2 * FD + (isL0 ? 0 : FD) + (ug0 + (tid & 7)) * 4);
  {
    const int row = tid >> 3, ul = tid & 7;
    c_reg = (isL0 ? cd0 : cd1)[row * D_ + ug0 + ul];
  }

  if (isL0) {
    for (int t = 0; t < T_; ++t) {
      cellw(t ? (ring1 + (long)(t - 1) * BD) : xd0,
            t ? dcnt : nullptr, 8u * (unsigned)t,
            t ? (ring0 + (long)(t - 1) * BD) : hd0i,
            t ? ccnt : nullptr, 8u * (unsigned)t,
            wlds, gl, c_reg, bias, ug0,
            ring0 + (long)t * BD, nullptr, 0);
      wg_arrive(ccnt, wg);
    }
  } else {
    for (int t = 0; t < T_; ++t) {
      cellw(ring0 + (long)t * BD, ccnt, 8u * (unsigned)(t + 1),
            t ? (ring1 + (long)(t - 1) * BD) : hd1i,
            t ? dcnt : nullptr, 8u * (unsigned)t,
            wlds, gl, c_reg, bias, ug0,
            ring1 + (long)t * BD, out + (long)t * D_, (long)T_ * D_);
      wg_arrive(dcnt, wg);
    }
  }
}

// ---------------------------------------------------------------------------
// Spectral norm prepass (unchanged, verified)
// ---------------------------------------------------------------------------
__device__ __forceinline__ const float* selW(int m, const float* a, const float* b,
                                             const float* c, const float* d) {
  const float* W;
  switch (m >> 1) { case 0: W = a; break; case 1: W = b; break;
                    case 2: W = c; break; default: W = d; }
  return W + (long)(m & 1) * FD * D_;
}
__device__ __forceinline__ const float* selU(int m, const float* a, const float* b,
                                             const float* c, const float* d) {
  const float* u;
  switch (m >> 1) { case 0: u = a; break; case 1: u = b; break;
                    case 2: u = c; break; default: u = d; }
  return u + (m & 1) * FD;
}

__global__ __launch_bounds__(256)
void k_unorm(const float* euih, const float* euhh, const float* duih, const float* duhh,
             float* uinv)
{
  const int m = blockIdx.x;
  const float* u = selU(m, euih, euhh, duih, duhh);
  float s = 0.f;
  for (int i = threadIdx.x; i < FD; i += 256) { float v = u[i]; s += v * v; }
  __shared__ float red[4];
  for (int off = 1; off < 64; off <<= 1) s += __shfl_xor(s, off);
  if ((threadIdx.x & 63) == 0) red[threadIdx.x >> 6] = s;
  __syncthreads();
  if (threadIdx.x == 0)
    uinv[m] = 1.0f / (sqrtf(red[0] + red[1] + red[2] + red[3]) + 1e-12f);
}

__global__ __launch_bounds__(256)
void k_v(const float* eWih, const float* eWhh, const float* dWih, const float* dWhh,
         const float* euih, const float* euhh, const float* duih, const float* duhh,
         const float* uinv, float* v, float* vss)
{
  __shared__ float us[FD];
  __shared__ float red[4];
  const int m = blockIdx.x >> 2, cb = blockIdx.x & 3;
  const float* W = selW(m, eWih, eWhh, dWih, dWhh);
  const float* u = selU(m, euih, euhh, duih, duhh);
  for (int i = threadIdx.x; i < FD; i += 256) us[i] = u[i];
  __syncthreads();
  const int j = cb * 256 + threadIdx.x;
  float acc = 0.f;
  for (int i = 0; i < FD; ++i) acc += W[(long)i * D_ + j] * us[i];
  acc *= uinv[m];
  v[m * D_ + j] = acc;
  float s = acc * acc;
  for (int off = 1; off < 64; off <<= 1) s += __shfl_xor(s, off);
  if ((threadIdx.x & 63) == 0) red[threadIdx.x >> 6] = s;
  __syncthreads();
  if (threadIdx.x == 0) vss[blockIdx.x] = red[0] + red[1] + red[2] + red[3];
}

__global__ __launch_bounds__(256)
void k_sig(const float* eWih, const float* eWhh, const float* dWih, const float* dWhh,
           const float* v, float* sgp)
{
  __shared__ float vl[D_];
  __shared__ float red[4];
  const int m = blockIdx.x >> 6, rb = blockIdx.x & 63;
  const float* W = selW(m, eWih, eWhh, dWih, dWhh);
  for (int i = threadIdx.x; i < D_; i += 256) vl[i] = v[m * D_ + i];
  __syncthreads();
  const int wv = threadIdx.x >> 6, lane = threadIdx.x & 63;
  float ssq = 0.f;
  for (int rr = 0; rr < 16; ++rr) {
    const int r = rb * 64 + wv * 16 + rr;
    const float* Wr = W + (long)r * D_;
    float d = 0.f;
    for (int j = lane; j < D_; j += 64) d += Wr[j] * vl[j];
    for (int off = 1; off < 64; off <<= 1) d += __shfl_xor(d, off);
    ssq += d * d;
  }
  if (lane == 0) red[wv] = ssq;
  __syncthreads();
  if (threadIdx.x == 0) sgp[blockIdx.x] = red[0] + red[1] + red[2] + red[3];
}

__global__ void k_fin(const float* vss, const float* sgp, float* rsig)
{
  const int m = threadIdx.x;
  if (m < 8) {
    float vn = sqrtf(vss[m * 4] + vss[m * 4 + 1] + vss[m * 4 + 2] + vss[m * 4 + 3]);
    float s2 = 0.f;
    for (int i = 0; i < 64; ++i) s2 += sgp[m * 64 + i];
    rsig[m] = (vn + 1e-12f) / sqrtf(s2);   // 1/sigma
  }
}

__global__ __launch_bounds__(256)
void k_pack(const float* eWih, const float* eWhh, const float* dWih, const float* dWhh,
            const float* rsig, u16* Wpe, u16* Wpd)
{
  const long idx = (long)blockIdx.x * 256 + threadIdx.x;
  const int k8   = (int)(idx & 255);
  const int np   = (int)((idx >> 8) & 4095);
  const int pair = (int)(idx >> 20);
  const int l = pair & 1, ed = pair >> 1;
  const int u = np >> 2, g = np & 3;
  const int srow = g * D_ + u;
  const int k = k8 * 8;
  const float* src; float sc;
  if (k < D_) {
    const float* Wih = ed ? dWih : eWih;
    src = Wih + ((long)(l * FD + srow)) * D_ + k;
    sc  = rsig[ed ? 4 + l : l];
  } else {
    const float* Whh = ed ? dWhh : eWhh;
    src = Whh + ((long)(l * FD + srow)) * D_ + (k - D_);
    sc  = rsig[ed ? 6 + l : 2 + l];
  }
  f4 a = *(const f4*)src;
  f4 b = *(const f4*)(src + 4);
  frag8 o;
  o[0] = (short)f2b(a.x * sc); o[1] = (short)f2b(a.y * sc);
  o[2] = (short)f2b(a.z * sc); o[3] = (short)f2b(a.w * sc);
  o[4] = (short)f2b(b.x * sc); o[5] = (short)f2b(b.y * sc);
  o[6] = (short)f2b(b.z * sc); o[7] = (short)f2b(b.w * sc);
  u16* dst = (ed ? Wpd : Wpe) + ((long)(l * FD + np)) * K2 + k;
  *(frag8*)dst = o;
}

__global__ void k_packb(const float* eb, const float* db, float* bp)
{
  const int idx = blockIdx.x * 256 + threadIdx.x;   // 4*4096
  const int j = idx & 4095, pair = idx >> 12;
  const int l = pair & 1, ed = pair >> 1;
  const float* b = (ed ? db : eb) + l * FD;
  bp[pair * FD + j] = b[(j & 3) * D_ + (j >> 2)];
}

// x [B,T,D] f32 -> xb [T][B][D] bf16
__global__ __launch_bounds__(512)
void k_xb(const float* __restrict__ x, u16* __restrict__ xb)
{
  const long i8 = ((long)blockIdx.x * 512 + threadIdx.x) * 8;
  const int d  = (int)(i8 & 1023);
  const int bt = (int)(i8 >> 10);
  const int b = bt & 63, t = bt >> 6;
  const float* src = x + ((long)b * T_ + t) * D_ + d;
  f4 a = *(const f4*)src;
  f4 c = *(const f4*)(src + 4);
  frag8 o;
  o[0] = (short)f2b(a.x); o[1] = (short)f2b(a.y);
  o[2] = (short)f2b(a.z); o[3] = (short)f2b(a.w);
  o[4] = (short)f2b(c.x); o[5] = (short)f2b(c.y);
  o[6] = (short)f2b(c.z); o[7] = (short)f2b(c.w);
  *(frag8*)(xb + i8) = o;
}

__global__ __launch_bounds__(512)
void k_xd0(const float* __restrict__ initial, u16* __restrict__ xd0)
{
  const int i8 = (blockIdx.x * 512 + threadIdx.x) * 8;   // < 65536
  const int d = i8 & 1023;
  f4 a = *(const f4*)(initial + d);
  f4 c = *(const f4*)(initial + d + 4);
  frag8 o;
  o[0] = (short)f2b(a.x); o[1] = (short)f2b(a.y);
  o[2] = (short)f2b(a.z); o[3] = (short)f2b(a.w);
  o[4] = (short)f2b(c.x); o[5] = (short)f2b(c.y);
  o[6] = (short)f2b(c.z); o[7] = (short)f2b(c.w);
  *(frag8*)(xd0 + i8) = o;
}

// ---------------------------------------------------------------------------
extern "C" void kernel_launch(void* const* d_in, const int* in_sizes, int n_in,
                              void* d_out, int out_size, void* d_ws, size_t ws_size,
                              hipStream_t stream)
{
  const float* x       = (const float*)d_in[0];
  const float* initial = (const float*)d_in[1];
  const float* eWih    = (const float*)d_in[2];
  const float* eWhh    = (const float*)d_in[3];
  const float* eb      = (const float*)d_in[4];
  const float* euih    = (const float*)d_in[5];
  const float* euhh    = (const float*)d_in[6];
  const float* dWih    = (const float*)d_in[7];
  const float* dWhh    = (const float*)d_in[8];
  const float* db      = (const float*)d_in[9];
  const float* duih    = (const float*)d_in[10];
  const float* duhh    = (const float*)d_in[11];
  const float* hmuW    = (const float*)d_in[12];
  const float* hmub    = (const float*)d_in[13];
  const float* hsgW    = (const float*)d_in[14];
  const float* hsgb    = (const float*)d_in[15];
  const float* houtW   = (const float*)d_in[16];
  const float* houtb   = (const float*)d_in[17];
  const float* cmuW    = (const float*)d_in[18];
  const float* cmub    = (const float*)d_in[19];
  const float* csgW    = (const float*)d_in[20];
  const float* csgb    = (const float*)d_in[21];
  const float* coutW   = (const float*)d_in[22];
  const float* coutb   = (const float*)d_in[23];
  const float* eps_h   = (const float*)d_in[24];
  const float* eps_c   = (const float*)d_in[25];

  char* w = (char*)d_ws;
  auto alloc = [&](size_t n) -> char* {
    char* p = w; w += (n + 255) & ~(size_t)255; return p;
  };
  u16*   Wpe   = (u16*)  alloc(2l * FD * K2 * 2);       // 32 MB
  u16*   Wpd   = (u16*)  alloc(2l * FD * K2 * 2);       // 32 MB
  u16*   xb    = (u16*)  alloc((long)T_ * BD * 2);      // 32 MB
  u16*   ring0 = (u16*)  alloc((long)T_ * BD * 2);      // 32 MB
  u16*   ring1 = (u16*)  alloc((long)T_ * BD * 2);      // 32 MB
  u16*   xd0   = (u16*)  alloc((long)BD * 2);
  u16*   hd0i  = (u16*)  alloc((long)BD * 2);
  u16*   hd1i  = (u16*)  alloc((long)BD * 2);
  float* ce0   = (float*)alloc((long)BD * 4);
  float* ce1   = (float*)alloc((long)BD * 4);
  float* cd0   = (float*)alloc((long)BD * 4);
  float* cd1   = (float*)alloc((long)BD * 4);
  float* bp    = (float*)alloc(4l * FD * 4);
  float* vv    = (float*)alloc(8l * D_ * 4);
  float* uinv  = (float*)alloc(64);
  float* vss   = (float*)alloc(256);
  float* sgp   = (float*)alloc(4096);
  float* rsig  = (float*)alloc(64);
  unsigned* bar = (unsigned*)alloc(40960);   // 5 sets x 16 lines x 512B

  hipMemsetAsync(bar, 0, 40960, stream);

  k_unorm<<<8,    256, 0, stream>>>(euih, euhh, duih, duhh, uinv);
  k_v    <<<32,   256, 0, stream>>>(eWih, eWhh, dWih, dWhh, euih, euhh, duih, duhh,
                                    uinv, vv, vss);
  k_sig  <<<512,  256, 0, stream>>>(eWih, eWhh, dWih, dWhh, vv, sgp);
  k_fin  <<<1,    64,  0, stream>>>(vss, sgp, rsig);
  k_pack <<<16384,256, 0, stream>>>(eWih, eWhh, dWih, dWhh, rsig, Wpe, Wpd);
  k_packb<<<64,   256, 0, stream>>>(eb, db, bp);
  k_xb   <<<4096, 512, 0, stream>>>(x, xb);
  k_xd0  <<<16,   512, 0, stream>>>(initial, xd0);

  float* out = (float*)d_out;
  float* muo = out + (long)B_ * T_ * D_;
  float* sgo = muo + 4l * B_ * G_;

  persist<<<NWG, 512, 0, stream>>>(Wpe, Wpd, bp, xb, xd0,
                                   ring0, ring1,
                                   ce0, ce1, hd0i, hd1i, cd0, cd1,
                                   hmuW, hmub, hsgW, hsgb, houtW, houtb,
                                   cmuW, cmub, csgW, csgb, coutW, coutb,
                                   eps_h, eps_c, out, muo, sgo, bar);
}

// Round 9
// 6482.120 us; speedup vs baseline: 2.9124x; 1.0912x over previous
//
#include <hip/hip_runtime.h>

// LSTM-VAE  B=64 T=256 D=1024 L=2 G=128 — persistent kernel, signal-driven.
// Round 9: LDS-mailbox waits — one poller wave per signal per WG; siblings
// spin on LDS. Kills the 512-wave LLC poll storm that throttled arrivals.
#define B_  64
#define T_  256
#define D_  1024
#define G_  128
#define FD  4096   // 4*D
#define K2  2048   // D (ih) + D (hh)
#define BD  65536  // B_*D_
#define NWG 256
#define CL  128    // u32 stride between counter lines (512 B)

typedef unsigned short u16;
typedef __attribute__((ext_vector_type(8))) short frag8;  // 8 bf16
typedef __attribute__((ext_vector_type(4))) float f4;

__device__ __forceinline__ u16 f2b(float f) {
  unsigned u = __float_as_uint(f);
  u += 0x7fffu + ((u >> 16) & 1u);
  return (u16)(u >> 16);
}
__device__ __forceinline__ float b2f(u16 s) {
  return __uint_as_float(((unsigned)s) << 16);
}
__device__ __forceinline__ float sigm(float x) { return 1.0f / (1.0f + __expf(-x)); }

// write-through coherent store (lands at LLC once vmcnt drains; no dirty L2)
__device__ __forceinline__ void stcoh(unsigned* p, unsigned w) {
  asm volatile("global_store_dword %0, %1, off sc0 sc1"
               :: "v"(p), "v"(w) : "memory");
}

// ---------------- group-signal primitives -----------------------------------
// Poller wave: lanes 0..15 poll 16 counter lines; when ALL >= tgt, lane 0
// publishes seq to the LDS flag. Whole wave returns.
__device__ __forceinline__ void poll16_pub(const unsigned* s, unsigned tgt,
                                           unsigned* lf, unsigned seq) {
  const int l = threadIdx.x & 63;
  for (;;) {
    bool ok = true;
    if (l < 16)
      ok = __hip_atomic_load(&s[l * CL], __ATOMIC_RELAXED,
                             __HIP_MEMORY_SCOPE_AGENT) >= tgt;
    if (__all(ok)) break;
    __builtin_amdgcn_s_sleep(4);
  }
  if (l == 0)
    __hip_atomic_store(lf, seq, __ATOMIC_RELAXED, __HIP_MEMORY_SCOPE_WORKGROUP);
  asm volatile("" ::: "memory");
}

// Sibling waves: spin on the LDS flag (no fabric traffic).
__device__ __forceinline__ void lds_wait(const unsigned* lf, unsigned seq) {
  while (__hip_atomic_load(lf, __ATOMIC_RELAXED,
                           __HIP_MEMORY_SCOPE_WORKGROUP) < seq)
    __builtin_amdgcn_s_sleep(1);
  asm volatile("" ::: "memory");
}

// arrive: drain this WG's (coherent) stores, then one atomic add.
__device__ __forceinline__ void wg_arrive(unsigned* cnt, int wg) {
  asm volatile("s_waitcnt vmcnt(0)" ::: "memory");
  __syncthreads();
  if (threadIdx.x == 0)
    __hip_atomic_fetch_add(&cnt[(wg & 15) * CL], 1u, __ATOMIC_RELAXED,
                           __HIP_MEMORY_SCOPE_AGENT);
}

// full-wave poll for phase-edge syncs (rare; contention irrelevant there)
__device__ __forceinline__ void wave_wait16(const unsigned* cnt, unsigned tgt) {
  const int l = threadIdx.x & 63;
  if (l < 16) {
    while (__hip_atomic_load(&cnt[l * CL], __ATOMIC_RELAXED,
                             __HIP_MEMORY_SCOPE_AGENT) < tgt)
      __builtin_amdgcn_s_sleep(2);
  }
  asm volatile("" ::: "memory");
}

// full-grid sync (phase edges only); fenced = release/acquire cache ops
__device__ __forceinline__ void fullsync(unsigned* g, unsigned ep, int wg,
                                         bool fenced) {
  if (fenced) __builtin_amdgcn_fence(__ATOMIC_RELEASE, "agent");
  wg_arrive(g, wg);
  wave_wait16(g, ep * 16u);
  __syncthreads();
  if (fenced) {
    __builtin_amdgcn_fence(__ATOMIC_ACQUIRE, "agent");
    __syncthreads();
  }
}

// ---------------- weight slice load: 32 rows x 2048 bf16, XOR-swizzled ------
__device__ __forceinline__ void load_weights(const u16* __restrict__ Wg, char* wlds) {
  const int t  = threadIdx.x;
  const int r  = t >> 4;           // 0..31
  const int c0 = t & 15;
  const char* src = (const char*)(Wg + (long)r * K2);
  char* dstrow = wlds + (r << 12);
  const int swz = (r & 7) << 4;
  #pragma unroll
  for (int i = 0; i < 16; ++i) {
    const int cb = (c0 + (i << 4)) << 4;      // chunk byte offset
    frag8 v = *(const frag8*)(src + cb);
    *(frag8*)(dstrow + (cb ^ swz)) = v;
  }
  __syncthreads();
}

// ---------------- one LSTM cell with LDS-mediated dependency waits ----------
// A0 (k<1024) gated by (c0p,t0); A1 (k>=1024) by (c1p,t1). null = ready.
// Wave 0 polls sig0, wave 4 polls sig1; waves 1-3 / 5-7 spin on LDS flags.
__device__ __forceinline__ void cellw(
    const u16* __restrict__ A0, const unsigned* c0p, unsigned t0,
    const u16* __restrict__ A1, const unsigned* c1p, unsigned t1,
    const char* wlds, float* gl, unsigned* lsf, unsigned seq,
    float& c_reg, const f4& bias, int ug0,
    u16* __restrict__ hout, float* __restrict__ fout, long fstride)
{
  const int tid = threadIdx.x;
  const int lane = tid & 63, wv = tid >> 6;
  const int mt = wv & 3, kh = wv >> 2;
  const int l15 = lane & 15, lgr = lane >> 4;

  f4 acc0 = (f4){0.f,0.f,0.f,0.f}, acc1 = (f4){0.f,0.f,0.f,0.f};
  const u16* Ab = kh ? A1 : A0;
  const unsigned* cp = kh ? c1p : c0p;
  const unsigned tg  = kh ? t1 : t0;
  unsigned* lf = lsf + kh;
  if (Ab) {
    if (cp) {
      if (mt == 0) poll16_pub(cp, tg, lf, seq);   // waves 0 and 4
      else         lds_wait(lf, seq);             // siblings: LDS spin
    }
    const u16* ap = Ab + (mt * 16 + l15) * 1024 + lgr * 8;
    const int kbyte0 = (kh << 11) + (lgr << 4);
    const int swz = (l15 & 7) << 4;
    const char* w0r = wlds + ((long)l15 << 12);
    const char* w1r = wlds + ((long)(16 + l15) << 12);
    #pragma unroll 8
    for (int kk = 0; kk < 32; ++kk) {
      frag8 af = *(const frag8*)(ap + kk * 32);
      const int kb = (kbyte0 + (kk << 6)) ^ swz;
      frag8 b0 = *(const frag8*)(w0r + kb);
      frag8 b1 = *(const frag8*)(w1r + kb);
      acc0 = __builtin_amdgcn_mfma_f32_16x16x32_bf16(af, b0, acc0, 0, 0, 0);
      acc1 = __builtin_amdgcn_mfma_f32_16x16x32_bf16(af, b1, acc1, 0, 0, 0);
    }
  }
  float* g = gl + kh * (64 * 32);
  const int orow = mt * 16 + lgr * 4;
  #pragma unroll
  for (int r = 0; r < 4; ++r) {
    g[(orow + r) * 32 + l15]      = acc0[r];
    g[(orow + r) * 32 + 16 + l15] = acc1[r];
  }
  __syncthreads();

  const int row = tid >> 3, ul = tid & 7;
  f4 p0 = *(const f4*)(gl + row * 32 + ul * 4);
  f4 p1 = *(const f4*)(gl + 64 * 32 + row * 32 + ul * 4);
  float iv = p0.x + p1.x + bias.x;
  float fv = p0.y + p1.y + bias.y;
  float gv = p0.z + p1.z + bias.z;
  float ov = p0.w + p1.w + bias.w;
  float cn = sigm(fv) * c_reg + sigm(iv) * tanhf(gv);
  float hh = sigm(ov) * tanhf(cn);
  c_reg = cn;
  unsigned hv = (unsigned)f2b(hh);
  unsigned other = __shfl_xor(hv, 1);
  if (!(ul & 1)) {
    unsigned word = hv | (other << 16);
    stcoh((unsigned*)(hout + row * 1024 + ug0 + ul), word);
  }
  if (fout) fout[(long)row * fstride + ug0 + ul] = hh;
  // NOTE: gl WAR protection comes from wg_arrive()'s __syncthreads.
}

// ---------------- VAE head, one (s,l,b) per WG ------------------------------
__device__ __forceinline__ void vae_wg(
    int bid, char* scr,
    const u16* h0f, const u16* h1f, const float* c0f, const float* c1f,
    const float* hmuW, const float* hmub, const float* hsgW, const float* hsgb,
    const float* houtW, const float* houtb,
    const float* cmuW, const float* cmub, const float* csgW, const float* csgb,
    const float* coutW, const float* coutb,
    const float* eps_h, const float* eps_c,
    float* muo, float* sgo, u16* hd0, u16* hd1, float* cd0, float* cd1)
{
  float* hrow = (float*)scr;
  float* muv  = hrow + 1024;
  float* sgv  = muv + 128;
  float* zz   = sgv + 128;
  const int tid = threadIdx.x;
  const int b = bid & 63, l = (bid >> 6) & 1, s = bid >> 7;

  if (s == 0) {
    const u16* h = (l ? h1f : h0f) + b * D_;
    for (int i = tid; i < D_; i += 512) hrow[i] = b2f(h[i]);
  } else {
    const float* c = (l ? c1f : c0f) + b * D_;
    for (int i = tid; i < D_; i += 512) hrow[i] = c[i];
  }
  __syncthreads();

  const float* muW = (s ? cmuW : hmuW) + (long)l * G_ * D_;
  const float* sgW = (s ? csgW : hsgW) + (long)l * G_ * D_;
  const float* mub = (s ? cmub : hmub) + l * G_;
  const float* sgb = (s ? csgb : hsgb) + l * G_;
  const int wv = tid >> 6, lane = tid & 63;
  for (int oi = wv; oi < 2 * G_; oi += 8) {
    const int g = (oi < G_) ? oi : oi - G_;
    const float* Wr = ((oi < G_) ? muW : sgW) + (long)g * D_;
    float d = 0.f;
    for (int j = lane; j < D_; j += 64) d += Wr[j] * hrow[j];
    for (int off = 1; off < 64; off <<= 1) d += __shfl_xor(d, off);
    if (lane == 0) {
      if (oi < G_) muv[g] = d + mub[g]; else sgv[g] = d + sgb[g];
    }
  }
  __syncthreads();
  if (tid < G_) {
    const int g = tid;
    const float mu = muv[g], sg = sgv[g];
    const float* ep = (s ? eps_c : eps_h) + ((long)l * B_ + b) * G_;
    zz[g] = mu + ep[g] * __expf(sg);
    muo[(long)bid * G_ + g] = mu;
    sgo[(long)bid * G_ + g] = sg;
  }
  __syncthreads();
  const float* oW  = (s ? coutW : houtW) + (long)l * D_ * G_;
  const float* obv = (s ? coutb : houtb) + l * D_;
  for (int i = 0; i < 2; ++i) {
    const int dd = i * 512 + tid;
    float acc = obv[dd];
    const float* Wr = oW + (long)dd * G_;
    #pragma unroll 4
    for (int g = 0; g < G_; ++g) acc += zz[g] * Wr[g];
    if (s == 0) { (l ? hd1 : hd0)[b * D_ + dd] = f2b(acc); }
    else        { (l ? cd1 : cd0)[b * D_ + dd] = acc; }
  }
  __syncthreads();
}

// ---------------- the persistent kernel -------------------------------------
__global__ __launch_bounds__(512, 1)
void persist(const u16* __restrict__ Wpe, const u16* __restrict__ Wpd,
             const float* __restrict__ bp,
             const u16* __restrict__ xb, const u16* __restrict__ xd0,
             u16* ring0, u16* ring1,
             float* ce0, float* ce1,
             u16* hd0i, u16* hd1i, float* cd0, float* cd1,
             const float* hmuW, const float* hmub, const float* hsgW, const float* hsgb,
             const float* houtW, const float* houtb,
             const float* cmuW, const float* cmub, const float* csgW, const float* csgb,
             const float* coutW, const float* coutb,
             const float* eps_h, const float* eps_c,
             float* out, float* muo, float* sgo, unsigned* bar)
{
  __shared__ __align__(16) char smem[147456 + 64]; // 128K weights + 16K + flags
  char*  wlds = smem;
  float* gl   = (float*)(smem + 131072);
  unsigned* lsf = (unsigned*)(smem + 147456);      // [0]=sig0 flag, [1]=sig1

  unsigned* gcnt = bar;
  unsigned* acnt = bar + 2048;
  unsigned* bcnt = bar + 4096;
  unsigned* ccnt = bar + 6144;
  unsigned* dcnt = bar + 8192;

  const int wg  = blockIdx.x;
  const bool isL0 = (wg < 128);
  const int wgL = wg & 127;
  const int ug0 = wgL * 8;
  const int tid = threadIdx.x;

  // ---- encoder phase (signal-driven, no grid barriers) ----
  if (tid == 0) { lsf[0] = 0; lsf[1] = 0; }        // load_weights syncs
  load_weights(Wpe + (isL0 ? 0l : (long)FD * K2) + (long)wgL * 32 * K2, wlds);
  f4 bias = *(const f4*)(bp + (isL0 ? 0 : FD) + (ug0 + (tid & 7)) * 4);
  float c_reg = 0.f;

  if (isL0) {
    for (int s = 0; s < T_; ++s) {
      cellw(xb + (long)s * BD, nullptr, 0,
            s ? (ring0 + (long)(s - 1) * BD) : nullptr,
            s ? acnt : nullptr, 8u * (unsigned)s,
            wlds, gl, lsf, (unsigned)(s + 1),
            c_reg, bias, ug0,
            ring0 + (long)s * BD, nullptr, 0);
      wg_arrive(acnt, wg);
    }
  } else {
    for (int t = 0; t < T_; ++t) {
      cellw(ring0 + (long)t * BD, acnt, 8u * (unsigned)(t + 1),
            t ? (ring1 + (long)(t - 1) * BD) : nullptr,
            t ? bcnt : nullptr, 8u * (unsigned)t,
            wlds, gl, lsf, (unsigned)(t + 1),
            c_reg, bias, ug0,
            ring1 + (long)t * BD, nullptr, 0);
      wg_arrive(bcnt, wg);
    }
  }
  // publish final c (normal stores; fenced sync follows)
  {
    const int row = tid >> 3, ul = tid & 7;
    (isL0 ? ce0 : ce1)[row * D_ + ug0 + ul] = c_reg;
  }
  fullsync(gcnt, 1, wg, true);

  // ---- VAE ----
  vae_wg(wg, (char*)gl,
         ring0 + 255l * BD, ring1 + 255l * BD, ce0, ce1,
         hmuW, hmub, hsgW, hsgb, houtW, houtb,
         cmuW, cmub, csgW, csgb, coutW, coutb,
         eps_h, eps_c, muo, sgo, hd0i, hd1i, cd0, cd1);
  fullsync(gcnt, 2, wg, true);   // also invalidates encoder-era ring lines

  // ---- decoder phase (signal-driven, 2 handoffs/step) ----
  if (tid == 0) { lsf[0] = 0; lsf[1] = 0; }        // load_weights syncs
  load_weights(Wpd + (isL0 ? 0l : (long)FD * K2) + (long)wgL * 32 * K2, wlds);
  bias = *(const f4*)(bp + 2 * FD + (isL0 ? 0 : FD) + (ug0 + (tid & 7)) * 4);
  {
    const int row = tid >> 3, ul = tid & 7;
    c_reg = (isL0 ? cd0 : cd1)[row * D_ + ug0 + ul];
  }

  if (isL0) {
    for (int t = 0; t < T_; ++t) {
      cellw(t ? (ring1 + (long)(t - 1) * BD) : xd0,
            t ? dcnt : nullptr, 8u * (unsigned)t,
            t ? (ring0 + (long)(t - 1) * BD) : hd0i,
            t ? ccnt : nullptr, 8u * (unsigned)t,
            wlds, gl, lsf, (unsigned)(t + 1),
            c_reg, bias, ug0,
            ring0 + (long)t * BD, nullptr, 0);
      wg_arrive(ccnt, wg);
    }
  } else {
    for (int t = 0; t < T_; ++t) {
      cellw(ring0 + (long)t * BD, ccnt, 8u * (unsigned)(t + 1),
            t ? (ring1 + (long)(t - 1) * BD) : hd1i,
            t ? dcnt : nullptr, 8u * (unsigned)t,
            wlds, gl, lsf, (unsigned)(t + 1),
            c_reg, bias, ug0,
            ring1 + (long)t * BD, out + (long)t * D_, (long)T_ * D_);
      wg_arrive(dcnt, wg);
    }
  }
}

// ---------------------------------------------------------------------------
// Spectral norm prepass (unchanged, verified)
// ---------------------------------------------------------------------------
__device__ __forceinline__ const float* selW(int m, const float* a, const float* b,
                                             const float* c, const float* d) {
  const float* W;
  switch (m >> 1) { case 0: W = a; break; case 1: W = b; break;
                    case 2: W = c; break; default: W = d; }
  return W + (long)(m & 1) * FD * D_;
}
__device__ __forceinline__ const float* selU(int m, const float* a, const float* b,
                                             const float* c, const float* d) {
  const float* u;
  switch (m >> 1) { case 0: u = a; break; case 1: u = b; break;
                    case 2: u = c; break; default: u = d; }
  return u + (m & 1) * FD;
}

__global__ __launch_bounds__(256)
void k_unorm(const float* euih, const float* euhh, const float* duih, const float* duhh,
             float* uinv)
{
  const int m = blockIdx.x;
  const float* u = selU(m, euih, euhh, duih, duhh);
  float s = 0.f;
  for (int i = threadIdx.x; i < FD; i += 256) { float v = u[i]; s += v * v; }
  __shared__ float red[4];
  for (int off = 1; off < 64; off <<= 1) s += __shfl_xor(s, off);
  if ((threadIdx.x & 63) == 0) red[threadIdx.x >> 6] = s;
  __syncthreads();
  if (threadIdx.x == 0)
    uinv[m] = 1.0f / (sqrtf(red[0] + red[1] + red[2] + red[3]) + 1e-12f);
}

__global__ __launch_bounds__(256)
void k_v(const float* eWih, const float* eWhh, const float* dWih, const float* dWhh,
         const float* euih, const float* euhh, const float* duih, const float* duhh,
         const float* uinv, float* v, float* vss)
{
  __shared__ float us[FD];
  __shared__ float red[4];
  const int m = blockIdx.x >> 2, cb = blockIdx.x & 3;
  const float* W = selW(m, eWih, eWhh, dWih, dWhh);
  const float* u = selU(m, euih, euhh, duih, duhh);
  for (int i = threadIdx.x; i < FD; i += 256) us[i] = u[i];
  __syncthreads();
  const int j = cb * 256 + threadIdx.x;
  float acc = 0.f;
  for (int i = 0; i < FD; ++i) acc += W[(long)i * D_ + j] * us[i];
  acc *= uinv[m];
  v[m * D_ + j] = acc;
  float s = acc * acc;
  for (int off = 1; off < 64; off <<= 1) s += __shfl_xor(s, off);
  if ((threadIdx.x & 63) == 0) red[threadIdx.x >> 6] = s;
  __syncthreads();
  if (threadIdx.x == 0) vss[blockIdx.x] = red[0] + red[1] + red[2] + red[3];
}

__global__ __launch_bounds__(256)
void k_sig(const float* eWih, const float* eWhh, const float* dWih, const float* dWhh,
           const float* v, float* sgp)
{
  __shared__ float vl[D_];
  __shared__ float red[4];
  const int m = blockIdx.x >> 6, rb = blockIdx.x & 63;
  const float* W = selW(m, eWih, eWhh, dWih, dWhh);
  for (int i = threadIdx.x; i < D_; i += 256) vl[i] = v[m * D_ + i];
  __syncthreads();
  const int wv = threadIdx.x >> 6, lane = threadIdx.x & 63;
  float ssq = 0.f;
  for (int rr = 0; rr < 16; ++rr) {
    const int r = rb * 64 + wv * 16 + rr;
    const float* Wr = W + (long)r * D_;
    float d = 0.f;
    for (int j = lane; j < D_; j += 64) d += Wr[j] * vl[j];
    for (int off = 1; off < 64; off <<= 1) d += __shfl_xor(d, off);
    ssq += d * d;
  }
  if (lane == 0) red[wv] = ssq;
  __syncthreads();
  if (threadIdx.x == 0) sgp[blockIdx.x] = red[0] + red[1] + red[2] + red[3];
}

__global__ void k_fin(const float* vss, const float* sgp, float* rsig)
{
  const int m = threadIdx.x;
  if (m < 8) {
    float vn = sqrtf(vss[m * 4] + vss[m * 4 + 1] + vss[m * 4 + 2] + vss[m * 4 + 3]);
    float s2 = 0.f;
    for (int i = 0; i < 64; ++i) s2 += sgp[m * 64 + i];
    rsig[m] = (vn + 1e-12f) / sqrtf(s2);   // 1/sigma
  }
}

__global__ __launch_bounds__(256)
void k_pack(const float* eWih, const float* eWhh, const float* dWih, const float* dWhh,
            const float* rsig, u16* Wpe, u16* Wpd)
{
  const long idx = (long)blockIdx.x * 256 + threadIdx.x;
  const int k8   = (int)(idx & 255);
  const int np   = (int)((idx >> 8) & 4095);
  const int pair = (int)(idx >> 20);
  const int l = pair & 1, ed = pair >> 1;
  const int u = np >> 2, g = np & 3;
  const int srow = g * D_ + u;
  const int k = k8 * 8;
  const float* src; float sc;
  if (k < D_) {
    const float* Wih = ed ? dWih : eWih;
    src = Wih + ((long)(l * FD + srow)) * D_ + k;
    sc  = rsig[ed ? 4 + l : l];
  } else {
    const float* Whh = ed ? dWhh : eWhh;
    src = Whh + ((long)(l * FD + srow)) * D_ + (k - D_);
    sc  = rsig[ed ? 6 + l : 2 + l];
  }
  f4 a = *(const f4*)src;
  f4 b = *(const f4*)(src + 4);
  frag8 o;
  o[0] = (short)f2b(a.x * sc); o[1] = (short)f2b(a.y * sc);
  o[2] = (short)f2b(a.z * sc); o[3] = (short)f2b(a.w * sc);
  o[4] = (short)f2b(b.x * sc); o[5] = (short)f2b(b.y * sc);
  o[6] = (short)f2b(b.z * sc); o[7] = (short)f2b(b.w * sc);
  u16* dst = (ed ? Wpd : Wpe) + ((long)(l * FD + np)) * K2 + k;
  *(frag8*)dst = o;
}

__global__ void k_packb(const float* eb, const float* db, float* bp)
{
  const int idx = blockIdx.x * 256 + threadIdx.x;   // 4*4096
  const int j = idx & 4095, pair = idx >> 12;
  const int l = pair & 1, ed = pair >> 1;
  const float* b = (ed ? db : eb) + l * FD;
  bp[pair * FD + j] = b[(j & 3) * D_ + (j >> 2)];
}

// x [B,T,D] f32 -> xb [T][B][D] bf16
__global__ __launch_bounds__(512)
void k_xb(const float* __restrict__ x, u16* __restrict__ xb)
{
  const long i8 = ((long)blockIdx.x * 512 + threadIdx.x) * 8;
  const int d  = (int)(i8 & 1023);
  const int bt = (int)(i8 >> 10);
  const int b = bt & 63, t = bt >> 6;
  const float* src = x + ((long)b * T_ + t) * D_ + d;
  f4 a = *(const f4*)src;
  f4 c = *(const f4*)(src + 4);
  frag8 o;
  o[0] = (short)f2b(a.x); o[1] = (short)f2b(a.y);
  o[2] = (short)f2b(a.z); o[3] = (short)f2b(a.w);
  o[4] = (short)f2b(c.x); o[5] = (short)f2b(c.y);
  o[6] = (short)f2b(c.z); o[7] = (short)f2b(c.w);
  *(frag8*)(xb + i8) = o;
}

__global__ __launch_bounds__(512)
void k_xd0(const float* __restrict__ initial, u16* __restrict__ xd0)
{
  const int i8 = (blockIdx.x * 512 + threadIdx.x) * 8;   // < 65536
  const int d = i8 & 1023;
  f4 a = *(const f4*)(initial + d);
  f4 c = *(const f4*)(initial + d + 4);
  frag8 o;
  o[0] = (short)f2b(a.x); o[1] = (short)f2b(a.y);
  o[2] = (short)f2b(a.z); o[3] = (short)f2b(a.w);
  o[4] = (short)f2b(c.x); o[5] = (short)f2b(c.y);
  o[6] = (short)f2b(c.z); o[7] = (short)f2b(c.w);
  *(frag8*)(xd0 + i8) = o;
}

// ---------------------------------------------------------------------------
extern "C" void kernel_launch(void* const* d_in, const int* in_sizes, int n_in,
                              void* d_out, int out_size, void* d_ws, size_t ws_size,
                              hipStream_t stream)
{
  const float* x       = (const float*)d_in[0];
  const float* initial = (const float*)d_in[1];
  const float* eWih    = (const float*)d_in[2];
  const float* eWhh    = (const float*)d_in[3];
  const float* eb      = (const float*)d_in[4];
  const float* euih    = (const float*)d_in[5];
  const float* euhh    = (const float*)d_in[6];
  const float* dWih    = (const float*)d_in[7];
  const float* dWhh    = (const float*)d_in[8];
  const float* db      = (const float*)d_in[9];
  const float* duih    = (const float*)d_in[10];
  const float* duhh    = (const float*)d_in[11];
  const float* hmuW    = (const float*)d_in[12];
  const float* hmub    = (const float*)d_in[13];
  const float* hsgW    = (const float*)d_in[14];
  const float* hsgb    = (const float*)d_in[15];
  const float* houtW   = (const float*)d_in[16];
  const float* houtb   = (const float*)d_in[17];
  const float* cmuW    = (const float*)d_in[18];
  const float* cmub    = (const float*)d_in[19];
  const float* csgW    = (const float*)d_in[20];
  const float* csgb    = (const float*)d_in[21];
  const float* coutW   = (const float*)d_in[22];
  const float* coutb   = (const float*)d_in[23];
  const float* eps_h   = (const float*)d_in[24];
  const float* eps_c   = (const float*)d_in[25];

  char* w = (char*)d_ws;
  auto alloc = [&](size_t n) -> char* {
    char* p = w; w += (n + 255) & ~(size_t)255; return p;
  };
  u16*   Wpe   = (u16*)  alloc(2l * FD * K2 * 2);       // 32 MB
  u16*   Wpd   = (u16*)  alloc(2l * FD * K2 * 2);       // 32 MB
  u16*   xb    = (u16*)  alloc((long)T_ * BD * 2);      // 32 MB
  u16*   ring0 = (u16*)  alloc((long)T_ * BD * 2);      // 32 MB
  u16*   ring1 = (u16*)  alloc((long)T_ * BD * 2);      // 32 MB
  u16*   xd0   = (u16*)  alloc((long)BD * 2);
  u16*   hd0i  = (u16*)  alloc((long)BD * 2);
  u16*   hd1i  = (u16*)  alloc((long)BD * 2);
  float* ce0   = (float*)alloc((long)BD * 4);
  float* ce1   = (float*)alloc((long)BD * 4);
  float* cd0   = (float*)alloc((long)BD * 4);
  float* cd1   = (float*)alloc((long)BD * 4);
  float* bp    = (float*)alloc(4l * FD * 4);
  float* vv    = (float*)alloc(8l * D_ * 4);
  float* uinv  = (float*)alloc(64);
  float* vss   = (float*)alloc(256);
  float* sgp   = (float*)alloc(4096);
  float* rsig  = (float*)alloc(64);
  unsigned* bar = (unsigned*)alloc(40960);   // 5 sets x 16 lines x 512B

  hipMemsetAsync(bar, 0, 40960, stream);

  k_unorm<<<8,    256, 0, stream>>>(euih, euhh, duih, duhh, uinv);
  k_v    <<<32,   256, 0, stream>>>(eWih, eWhh, dWih, dWhh, euih, euhh, duih, duhh,
                                    uinv, vv, vss);
  k_sig  <<<512,  256, 0, stream>>>(eWih, eWhh, dWih, dWhh, vv, sgp);
  k_fin  <<<1,    64,  0, stream>>>(vss, sgp, rsig);
  k_pack <<<16384,256, 0, stream>>>(eWih, eWhh, dWih, dWhh, rsig, Wpe, Wpd);
  k_packb<<<64,   256, 0, stream>>>(eb, db, bp);
  k_xb   <<<4096, 512, 0, stream>>>(x, xb);
  k_xd0  <<<16,   512, 0, stream>>>(initial, xd0);

  float* out = (float*)d_out;
  float* muo = out + (long)B_ * T_ * D_;
  float* sgo = muo + 4l * B_ * G_;

  persist<<<NWG, 512, 0, stream>>>(Wpe, Wpd, bp, xb, xd0,
                                   ring0, ring1,
                                   ce0, ce1, hd0i, hd1i, cd0, cd1,
                                   hmuW, hmub, hsgW, hsgb, houtW, houtb,
                                   cmuW, cmub, csgW, csgb, coutW, coutb,
                                   eps_h, eps_c, out, muo, sgo, bar);
}